// Round 13
// baseline (201.342 us; speedup 1.0000x reference)
//
#include <hip/hip_runtime.h>
#include <hip/hip_fp16.h>

#define NN 50000
#define NE 800000
#define NBKT 391          // ceil(50000/128) buckets of 128 nodes
#define P1B 128           // blocks in hist/scatter passes

typedef __attribute__((ext_vector_type(8))) _Float16 half8v;  // 8 fp16 in 4 VGPRs
typedef __attribute__((ext_vector_type(4))) float f32x4;

static inline size_t align_up(size_t x, size_t a) { return (x + a - 1) & ~(a - 1); }

union U8 {
    ushort4 u;
    __half2 h[2];
};

__device__ __forceinline__ float4 u8_to_f4(ushort4 uu) {
    U8 c;
    c.u = uu;
    float2 f01 = __half22float2(c.h[0]);
    float2 f23 = __half22float2(c.h[1]);
    return make_float4(f01.x, f01.y, f23.x, f23.y);
}

__device__ __forceinline__ ushort4 f4_to_u8(float4 v) {
    U8 c;
    c.h[0] = __floats2half2_rn(v.x, v.y);
    c.h[1] = __floats2half2_rn(v.z, v.w);
    return c.u;
}

// async global->LDS, 16B per lane (dest = wave-uniform base + lane*16)
__device__ __forceinline__ void gload_lds16(const unsigned short* g, unsigned short* l) {
    __builtin_amdgcn_global_load_lds(
        (const __attribute__((address_space(1))) unsigned int*)g,
        (__attribute__((address_space(3))) unsigned int*)l,
        16, 0, 0);
}

// int64-vs-int32 edge layout probe (values < 2^31 => odd words zero)
__device__ __forceinline__ int detect64(const int* __restrict__ e) {
    int ok = 1;
    for (int k = 1; k < 64; k += 2) ok &= (e[k] == 0);
    return ok;
}

// ---------------------------------------------------------------------------
// P1: per-block bucket histogram -> plain writes to base[block][bucket];
// spare lanes also do the weight transpose+cast (fused prep_weights)
// ---------------------------------------------------------------------------
__global__ __launch_bounds__(256) void bucket_hist(const int* __restrict__ e,
                                                   int* __restrict__ base,
                                                   const float* __restrict__ W1,
                                                   const float* __restrict__ W2,
                                                   const float* __restrict__ W3,
                                                   unsigned short* __restrict__ w1t,
                                                   unsigned short* __restrict__ w2t,
                                                   unsigned short* __restrict__ w3t,
                                                   int E) {
    __shared__ int hist[NBKT];
    const int is64 = detect64(e);
    for (int t = threadIdx.x; t < NBKT; t += 256) hist[t] = 0;
    __syncthreads();
    const int chunk = (E + P1B - 1) / P1B;
    const int b0 = blockIdx.x * chunk;
    const int b1 = min(E, b0 + chunk);
    for (int i = b0 + threadIdx.x; i < b1; i += 256) {
        int d = is64 ? e[2 * (E + i)] : e[E + i];
        atomicAdd(&hist[d >> 7], 1);
    }
    // fused weight prep (grid-stride over 69632 elems)
    for (int i = blockIdx.x * 256 + threadIdx.x; i < 69632; i += P1B * 256) {
        const float* W;
        unsigned short* th;
        int K, M, j;
        if (i < 32768)      { W = W1; th = w1t; K = 128; M = 256; j = i; }
        else if (i < 65536) { W = W2; th = w2t; K = 256; M = 128; j = i - 32768; }
        else                { W = W3; th = w3t; K = 128; M = 32;  j = i - 65536; }
        int k = j / M, m = j % M;
        th[(size_t)m * K + k] = __half_as_ushort(__float2half_rn(W[j]));
    }
    __syncthreads();
    for (int t = threadIdx.x; t < NBKT; t += 256)
        base[blockIdx.x * NBKT + t] = hist[t];
}

// ---------------------------------------------------------------------------
// P2: column prefix over base[P1B][NBKT] (per-block exclusive offsets) +
// bucket exclusive scan -> bstart[0..NBKT]. One block, 512 threads.
// ---------------------------------------------------------------------------
__global__ __launch_bounds__(512) void colsum_scan(int* __restrict__ base,
                                                   int* __restrict__ bstart) {
    __shared__ int s[512];
    const int t = threadIdx.x;
    int total = 0;
    if (t < NBKT) {
        for (int b0 = 0; b0 < P1B; b0 += 8) {
            int v[8];
#pragma unroll
            for (int u = 0; u < 8; ++u) v[u] = base[(size_t)(b0 + u) * NBKT + t];
#pragma unroll
            for (int u = 0; u < 8; ++u) {
                int nv = v[u];
                base[(size_t)(b0 + u) * NBKT + t] = total;
                total += nv;
            }
        }
    }
    s[t] = (t < NBKT) ? total : 0;
    __syncthreads();
    for (int off = 1; off < 512; off <<= 1) {
        int tv = (t >= off) ? s[t - off] : 0;
        __syncthreads();
        s[t] += tv;
        __syncthreads();
    }
    if (t < NBKT) bstart[t] = s[t] - total;
    if (t == 0) bstart[NBKT] = s[511];  // total = E
}

// ---------------------------------------------------------------------------
// P3: scatter packed edges (src u16 | dst_local u7) into bucket-binned order
// ---------------------------------------------------------------------------
__global__ __launch_bounds__(256) void bucket_scatter(const int* __restrict__ e,
                                                      const int* __restrict__ bstart,
                                                      const int* __restrict__ base,
                                                      unsigned* __restrict__ pairs, int E) {
    __shared__ int cur[NBKT];
    const int is64 = detect64(e);
    for (int t = threadIdx.x; t < NBKT; t += 256)
        cur[t] = bstart[t] + base[blockIdx.x * NBKT + t];
    __syncthreads();
    const int chunk = (E + P1B - 1) / P1B;
    const int b0 = blockIdx.x * chunk;
    const int b1 = min(E, b0 + chunk);
    for (int i = b0 + threadIdx.x; i < b1; i += 256) {
        int s = is64 ? e[2 * i] : e[i];
        int d = is64 ? e[2 * (E + i)] : e[E + i];
        int pos = atomicAdd(&cur[d >> 7], 1);
        pairs[pos] = (unsigned)s | ((unsigned)(d & 127) << 16);
    }
}

// ---------------------------------------------------------------------------
// P4: one block per bucket. (1) local deg count + scan -> ninfo{beg,deg}/dinv;
// (2) LDS-cursor scatter src -> contiguous u16 CSR range; (3) fused cast of
// this bucket's x rows to pre-scaled fp16 (x' = dinv ⊙ x).
// ---------------------------------------------------------------------------
__global__ __launch_bounds__(256) void bucket_finalize(const unsigned* __restrict__ pairs,
                                                       const int* __restrict__ bstart,
                                                       const float* __restrict__ x,
                                                       int2* __restrict__ ninfo,
                                                       float* __restrict__ dinv,
                                                       unsigned short* __restrict__ csr,
                                                       unsigned short* __restrict__ xh, int n) {
    __shared__ int ldeg[128];
    __shared__ int lscan[128];
    __shared__ int cur[128];
    __shared__ float sdinv[128];
    const int bkt = blockIdx.x;
    const int s0 = bstart[bkt], s1 = bstart[bkt + 1];
    if (threadIdx.x < 128) ldeg[threadIdx.x] = 0;
    __syncthreads();
    for (int i = s0 + threadIdx.x; i < s1; i += 256)
        atomicAdd(&ldeg[pairs[i] >> 16], 1);
    __syncthreads();
    if (threadIdx.x < 128) lscan[threadIdx.x] = ldeg[threadIdx.x];
    __syncthreads();
    for (int off = 1; off < 128; off <<= 1) {
        int v = 0;
        if (threadIdx.x < 128 && threadIdx.x >= off) v = lscan[threadIdx.x - off];
        __syncthreads();
        if (threadIdx.x < 128) lscan[threadIdx.x] += v;
        __syncthreads();
    }
    if (threadIdx.x < 128) {
        int node = (bkt << 7) + threadIdx.x;
        int exc = s0 + lscan[threadIdx.x] - ldeg[threadIdx.x];
        cur[threadIdx.x] = exc;
        float di = rsqrtf((float)(ldeg[threadIdx.x] + 1));  // +1 self-loop
        sdinv[threadIdx.x] = di;
        if (node < n) {
            ninfo[node] = make_int2(exc, ldeg[threadIdx.x]);
            dinv[node] = di;
        }
    }
    __syncthreads();
    // csr scatter (u16 src)
    for (int i = s0 + threadIdx.x; i < s1; i += 256) {
        unsigned pr = pairs[i];
        int pos = atomicAdd(&cur[pr >> 16], 1);
        csr[pos] = (unsigned short)(pr & 0xFFFFu);
    }
    // fused cast: x rows of this bucket -> pre-scaled fp16 (linear, coalesced)
    for (int idx = threadIdx.x; idx < 128 * 32; idx += 256) {
        int ln = idx >> 5;         // local node
        int c4 = idx & 31;         // float4 chunk within row (128 feats)
        int node = (bkt << 7) + ln;
        if (node < n) {
            float4 v = ((const float4*)x)[(size_t)node * 32 + c4];
            float s = sdinv[ln];
            v.x *= s; v.y *= s; v.z *= s; v.w *= s;
            ((ushort4*)xh)[(size_t)node * 32 + c4] = f4_to_u8(v);
        }
    }
}

// ---------------------------------------------------------------------------
// FUSED layer-1+2 GEMM: per 128-row tile,
//   h1 = relu(agg0 @ W1 + b1)   [128 x 256]  (kept in LDS, never hits HBM)
//   h2' = dinv ⊙ (h1 @ W2)      [128 x 128]  (fp16 out)
// ---------------------------------------------------------------------------
__global__ __launch_bounds__(256) void gemm12(
    const unsigned short* __restrict__ A,     // agg0 [N][128] fp16
    const unsigned short* __restrict__ W1t,   // [256][128] fp16
    const unsigned short* __restrict__ W2t,   // [128][256] fp16
    const float* __restrict__ b1,
    const float* __restrict__ dinv,
    unsigned short* __restrict__ H2,          // [N][128] fp16 (scaled)
    int N) {
    __shared__ unsigned short sA[128][128];   // 32KB, swizzled chunks
    __shared__ unsigned short sW[128][128];   // 32KB, swizzled, reused 4x
    __shared__ unsigned short sH[128][136];   // 34.8KB, padded (16B-aligned rows)

    const int tid = threadIdx.x;
    const int lane = tid & 63;
    const int w = tid >> 6;
    const int wr = w >> 1, wc = w & 1;        // 2x2 waves over 128x128
    const int row0 = blockIdx.x * 128;
    const int rsel = lane & 15;
    const int cq = lane >> 4;                 // 0..3

    // stage A tile (rows x K=128): 2048 16B-chunks, slot s holds chunk (s&8)|((s^r)&7)
#pragma unroll
    for (int b = 0; b < 2048; b += 256) {
        int idx = b + tid;
        int r = idx >> 4, s = idx & 15;
        int gr = row0 + r;
        int sp = (s & 8) | ((s ^ r) & 7);
        if (gr < N) gload_lds16(&A[(size_t)gr * 128 + sp * 8], &sA[0][0] + idx * 8);
        // rows >= N: stale LDS; those output rows are never stored
    }

    f32x4 acc2[4][4];
#pragma unroll
    for (int m = 0; m < 4; ++m)
#pragma unroll
        for (int nn = 0; nn < 4; ++nn) {
            f32x4 z = {0.f, 0.f, 0.f, 0.f};
            acc2[m][nn] = z;
        }

    for (int half = 0; half < 2; ++half) {
        __syncthreads();  // drains A-stage (half 0) / prior acc2 reads of sW (half 1)
        // stage W1 half: h1-cols half*128..+127, K=128
#pragma unroll
        for (int b = 0; b < 2048; b += 256) {
            int idx = b + tid;
            int r = idx >> 4, s = idx & 15;
            int sp = (s & 8) | ((s ^ r) & 7);
            gload_lds16(&W1t[(size_t)(half * 128 + r) * 128 + sp * 8], &sW[0][0] + idx * 8);
        }
        __syncthreads();

        // acc1 = sA @ sW^T   (output 128x128, K=128)
        f32x4 acc1[4][4];
#pragma unroll
        for (int m = 0; m < 4; ++m)
#pragma unroll
            for (int nn = 0; nn < 4; ++nn) {
                f32x4 z = {0.f, 0.f, 0.f, 0.f};
                acc1[m][nn] = z;
            }
#pragma unroll
        for (int ks = 0; ks < 4; ++ks) {
            half8v af[4], wf[4];
            int c = ks * 4 + cq;
#pragma unroll
            for (int m = 0; m < 4; ++m) {
                int rr = wr * 64 + m * 16 + rsel;
                int cp = (c & 8) | ((c ^ rr) & 7);
                af[m] = *(const half8v*)&sA[rr][cp * 8];
            }
#pragma unroll
            for (int nn = 0; nn < 4; ++nn) {
                int rr = wc * 64 + nn * 16 + rsel;
                int cp = (c & 8) | ((c ^ rr) & 7);
                wf[nn] = *(const half8v*)&sW[rr][cp * 8];
            }
#pragma unroll
            for (int m = 0; m < 4; ++m)
#pragma unroll
                for (int nn = 0; nn < 4; ++nn)
                    acc1[m][nn] = __builtin_amdgcn_mfma_f32_16x16x32_f16(af[m], wf[nn], acc1[m][nn], 0, 0, 0);
        }

        // bias+relu -> fp16 -> sH (row-major h1 half)
        float b1v[4];
#pragma unroll
        for (int nn = 0; nn < 4; ++nn)
            b1v[nn] = b1[half * 128 + wc * 64 + nn * 16 + rsel];
#pragma unroll
        for (int m = 0; m < 4; ++m)
#pragma unroll
            for (int nn = 0; nn < 4; ++nn)
#pragma unroll
                for (int r = 0; r < 4; ++r) {
                    int rl = wr * 64 + m * 16 + cq * 4 + r;
                    int cl = wc * 64 + nn * 16 + rsel;
                    float v = fmaxf(acc1[m][nn][r] + b1v[nn], 0.f);
                    sH[rl][cl] = __half_as_ushort(__float2half_rn(v));
                }
        __syncthreads();  // sH complete; safe to overwrite sW

        // stage W2 K-slice: rows (h2 cols) 0..127, K in [half*128, half*128+128)
#pragma unroll
        for (int b = 0; b < 2048; b += 256) {
            int idx = b + tid;
            int r = idx >> 4, s = idx & 15;
            int sp = (s & 8) | ((s ^ r) & 7);
            gload_lds16(&W2t[(size_t)r * 256 + half * 128 + sp * 8], &sW[0][0] + idx * 8);
        }
        __syncthreads();

        // acc2 += sH @ sW^T  (K=128 local)
#pragma unroll
        for (int ks = 0; ks < 4; ++ks) {
            half8v ah[4], wf[4];
            int koff = ks * 32 + cq * 8;
            int c = ks * 4 + cq;
#pragma unroll
            for (int m = 0; m < 4; ++m) {
                int rr = wr * 64 + m * 16 + rsel;
                ah[m] = *(const half8v*)&sH[rr][koff];
            }
#pragma unroll
            for (int nn = 0; nn < 4; ++nn) {
                int rr = wc * 64 + nn * 16 + rsel;
                int cp = (c & 8) | ((c ^ rr) & 7);
                wf[nn] = *(const half8v*)&sW[rr][cp * 8];
            }
#pragma unroll
            for (int m = 0; m < 4; ++m)
#pragma unroll
                for (int nn = 0; nn < 4; ++nn)
                    acc2[m][nn] = __builtin_amdgcn_mfma_f32_16x16x32_f16(ah[m], wf[nn], acc2[m][nn], 0, 0, 0);
        }
    }

    // epilogue: h2' = dinv ⊙ acc2, fp16 out
#pragma unroll
    for (int m = 0; m < 4; ++m)
#pragma unroll
        for (int r = 0; r < 4; ++r) {
            int row = row0 + wr * 64 + m * 16 + cq * 4 + r;
            if (row >= N) continue;
            float rs = dinv[row];
#pragma unroll
            for (int nn = 0; nn < 4; ++nn) {
                int col = wc * 64 + nn * 16 + rsel;
                H2[(size_t)row * 128 + col] =
                    __half_as_ushort(__float2half_rn(acc2[m][nn][r] * rs));
            }
        }
}

// ---------------------------------------------------------------------------
// CSR aggregation (standalone) over PRE-SCALED fp16 table h' = dinv ⊙ h:
// out[d] = dinv[d] * (h'[d] + Σ h'[s]) + bias ; 16-deep batched gathers
// ---------------------------------------------------------------------------
__device__ __forceinline__ float4 add4(float4 v, float4 a) {
    a.x += v.x; a.y += v.y; a.z += v.z; a.w += v.w;
    return a;
}

template <int F, int NPB, bool BIAS, bool RELU, bool OUTF16>
__global__ __launch_bounds__((F / 4) * NPB) void agg4h(
    const unsigned short* __restrict__ h, const int2* __restrict__ ninfo,
    const unsigned short* __restrict__ csr,
    const float* __restrict__ dinv, const float* __restrict__ bias,
    float* __restrict__ outf, unsigned short* __restrict__ outh, int n) {
    constexpr int L = F / 4;
    const int local = threadIdx.x / L;
    const int lane = threadIdx.x % L;
    const int node = blockIdx.x * NPB + local;
    if (node >= n) return;

    const ushort4* __restrict__ h4 = (const ushort4*)h;
    const float di = dinv[node];
    const int2 info = ninfo[node];
    const int beg = info.x;
    const int num = info.y;

    float4 acc0 = u8_to_f4(h4[(size_t)node * L + lane]);  // self term h'[d]
    float4 acc1 = make_float4(0.f, 0.f, 0.f, 0.f);

    for (int e = 0; e < num; e += 16) {
        int c[16];
        ushort4 raw[16];
#pragma unroll
        for (int u = 0; u < 16; ++u) {
            int idx = min(e + u, num - 1);
            c[u] = csr[beg + idx];
        }
#pragma unroll
        for (int u = 0; u < 16; ++u) raw[u] = h4[(size_t)c[u] * L + lane];
#pragma unroll
        for (int u = 0; u < 8; ++u) {
            float4 v = u8_to_f4(raw[u]);
            if (e + u < num) acc0 = add4(v, acc0);
        }
#pragma unroll
        for (int u = 8; u < 16; ++u) {
            float4 v = u8_to_f4(raw[u]);
            if (e + u < num) acc1 = add4(v, acc1);
        }
    }
    float4 acc = add4(acc1, acc0);
    acc.x *= di; acc.y *= di; acc.z *= di; acc.w *= di;
    if (BIAS) {
        const float4 b = ((const float4*)bias)[lane];
        acc.x += b.x; acc.y += b.y; acc.z += b.z; acc.w += b.w;
    }
    if (RELU) {
        acc.x = fmaxf(acc.x, 0.f); acc.y = fmaxf(acc.y, 0.f);
        acc.z = fmaxf(acc.z, 0.f); acc.w = fmaxf(acc.w, 0.f);
    }
    if constexpr (OUTF16) {
        ((ushort4*)outh)[(size_t)node * L + lane] = f4_to_u8(acc);
    } else {
        ((float4*)outf)[(size_t)node * L + lane] = acc;
    }
}

// ---------------------------------------------------------------------------
// FUSED layer-2 agg + layer-3 GEMM: per node,
//   x3 = relu(dinv[d]*(h2'[d] + Σ h2'[s]) + b2)      (fp16, staged in LDS)
//   h3'[d][j] = dinv[d] * Σ_k x3[k]·W3t[j][k]        (j = 0..31, fp16 out)
// block = 256 threads = 8 nodes × 32 lanes; NO early return (barrier inside).
// ---------------------------------------------------------------------------
__global__ __launch_bounds__(256) void agg_gemm3(
    const unsigned short* __restrict__ h, const int2* __restrict__ ninfo,
    const unsigned short* __restrict__ csr,
    const float* __restrict__ dinv, const float* __restrict__ b2,
    const unsigned short* __restrict__ w3t,   // [32][128] fp16
    unsigned short* __restrict__ h3s, int n) {
    __shared__ unsigned short sX[8][132];     // x3 rows, padded

    const int local = threadIdx.x >> 5;       // node in block (0..7)
    const int lane = threadIdx.x & 31;
    const int node = blockIdx.x * 8 + local;
    const bool valid = node < n;

    const ushort4* __restrict__ h4 = (const ushort4*)h;
    const float di = valid ? dinv[node] : 0.f;
    int2 info = valid ? ninfo[node] : make_int2(0, 0);
    const int beg = info.x;
    const int num = info.y;

    float4 acc0 = valid ? u8_to_f4(h4[(size_t)node * 32 + lane])
                        : make_float4(0.f, 0.f, 0.f, 0.f);
    float4 acc1 = make_float4(0.f, 0.f, 0.f, 0.f);

    for (int e = 0; e < num; e += 16) {
        int c[16];
        ushort4 raw[16];
#pragma unroll
        for (int u = 0; u < 16; ++u) {
            int idx = min(e + u, num - 1);
            c[u] = csr[beg + idx];
        }
#pragma unroll
        for (int u = 0; u < 16; ++u) raw[u] = h4[(size_t)c[u] * 32 + lane];
#pragma unroll
        for (int u = 0; u < 8; ++u) {
            float4 v = u8_to_f4(raw[u]);
            if (e + u < num) acc0 = add4(v, acc0);
        }
#pragma unroll
        for (int u = 8; u < 16; ++u) {
            float4 v = u8_to_f4(raw[u]);
            if (e + u < num) acc1 = add4(v, acc1);
        }
    }
    float4 acc = add4(acc1, acc0);
    acc.x *= di; acc.y *= di; acc.z *= di; acc.w *= di;
    {
        const float4 b = ((const float4*)b2)[lane];
        acc.x = fmaxf(acc.x + b.x, 0.f);
        acc.y = fmaxf(acc.y + b.y, 0.f);
        acc.z = fmaxf(acc.z + b.z, 0.f);
        acc.w = fmaxf(acc.w + b.w, 0.f);
    }
    // stage x3 (fp16-rounded, same numerics as before) into LDS
    *(ushort4*)&sX[local][lane * 4] = f4_to_u8(acc);
    __syncthreads();

    // matvec: lane j computes h3'[node][j] = di * Σ_k x3[k] * W3t[j][k]
    const ushort4* __restrict__ w4 = (const ushort4*)(w3t + (size_t)lane * 128);
    float4 p = make_float4(0.f, 0.f, 0.f, 0.f);
#pragma unroll
    for (int c = 0; c < 32; ++c) {
        float4 xv = u8_to_f4(*(const ushort4*)&sX[local][c * 4]);  // broadcast
        float4 wv = u8_to_f4(w4[c]);                               // L1-hot
        p.x = fmaf(xv.x, wv.x, p.x);
        p.y = fmaf(xv.y, wv.y, p.y);
        p.z = fmaf(xv.z, wv.z, p.z);
        p.w = fmaf(xv.w, wv.w, p.w);
    }
    float r = (p.x + p.y) + (p.z + p.w);
    if (valid) h3s[(size_t)node * 32 + lane] = __half_as_ushort(__float2half_rn(r * di));
}

// ---------------------------------------------------------------------------
extern "C" void kernel_launch(void* const* d_in, const int* in_sizes, int n_in,
                              void* d_out, int out_size, void* d_ws, size_t ws_size,
                              hipStream_t stream) {
    const float* x   = (const float*)d_in[0];
    const int*   eix = (const int*)d_in[1];
    const float* W1  = (const float*)d_in[2];
    const float* b1  = (const float*)d_in[3];
    const float* W2  = (const float*)d_in[4];
    const float* b2  = (const float*)d_in[5];
    const float* W3  = (const float*)d_in[6];
    const float* b3  = (const float*)d_in[7];
    float* out = (float*)d_out;

    const int n = NN, E = NE;

    char* p = (char*)d_ws;
    auto alloc = [&](size_t bytes) { void* r = (void*)p; p += align_up(bytes, 256); return r; };
    int2*  ninfo     = (int2*)alloc((size_t)n * 8);
    float* dinv      = (float*)alloc((size_t)n * 4);
    int*   bstart    = (int*)alloc((size_t)(NBKT + 1) * 4);
    int*   base      = (int*)alloc((size_t)P1B * NBKT * 4);
    unsigned* pairs  = (unsigned*)alloc((size_t)E * 4);
    unsigned short* csr = (unsigned short*)alloc((size_t)E * 2);
    unsigned short* w1t = (unsigned short*)alloc((size_t)128 * 256 * 2);
    unsigned short* w2t = (unsigned short*)alloc((size_t)256 * 128 * 2);
    unsigned short* w3t = (unsigned short*)alloc((size_t)128 * 32 * 2);
    unsigned short* xh   = (unsigned short*)alloc((size_t)n * 128 * 2);  // x'  fp16
    unsigned short* agg0 = (unsigned short*)alloc((size_t)n * 128 * 2);  // agg0 fp16
    unsigned short* h2s  = (unsigned short*)alloc((size_t)n * 128 * 2);  // h2' fp16 (scaled)
    unsigned short* h3s  = (unsigned short*)alloc((size_t)n * 32 * 2);   // h3' fp16 (scaled)
    (void)ws_size; (void)in_sizes; (void)n_in; (void)out_size;

    // ---- CSR build: hist(+weight prep) -> colsum+scan -> scatter ->
    //      finalize(+fused x cast)
    bucket_hist<<<P1B, 256, 0, stream>>>(eix, base, W1, W2, W3, w1t, w2t, w3t, E);
    colsum_scan<<<1, 512, 0, stream>>>(base, bstart);
    bucket_scatter<<<P1B, 256, 0, stream>>>(eix, bstart, base, pairs, E);
    bucket_finalize<<<NBKT, 256, 0, stream>>>(pairs, bstart, x, ninfo, dinv, csr, xh, n);

    const int RB = (n + 127) / 128;  // 391 row blocks

    // ---- layer 1 agg: agg0 = A_norm-gather(x') (fp16)
    agg4h<128, 8, false, false, true><<<(n + 7) / 8, 256, 0, stream>>>(
        xh, ninfo, csr, dinv, nullptr, nullptr, agg0, n);

    // ---- FUSED gemm1+gemm2: h2' = dinv ⊙ (relu(agg0 @ W1 + b1) @ W2) (fp16)
    gemm12<<<RB, 256, 0, stream>>>(agg0, w1t, w2t, b1, dinv, h2s, n);

    // ---- FUSED layer-2 agg + layer-3 gemm: h3' = dinv ⊙ (relu(agg(h2')+b2) @ W3)
    agg_gemm3<<<(n + 7) / 8, 256, 0, stream>>>(
        h2s, ninfo, csr, dinv, b2, w3t, h3s, n);

    // ---- final agg: out = agg(h3') + b3 (f32)
    agg4h<32, 32, true, false, false><<<(n + 31) / 32, 256, 0, stream>>>(
        h3s, ninfo, csr, dinv, b3, out, nullptr, n);
}

// Round 14
// 157.207 us; speedup vs baseline: 1.2808x; 1.2808x over previous
//
#include <hip/hip_runtime.h>
#include <hip/hip_fp16.h>

#define NN 50000
#define NE 800000
#define NBKT 391          // ceil(50000/128) buckets of 128 nodes
#define P1B 256           // blocks in hist/scatter passes

typedef __attribute__((ext_vector_type(8))) _Float16 half8v;  // 8 fp16 in 4 VGPRs
typedef __attribute__((ext_vector_type(4))) float f32x4;

static inline size_t align_up(size_t x, size_t a) { return (x + a - 1) & ~(a - 1); }

union U8 {
    ushort4 u;
    __half2 h[2];
};

__device__ __forceinline__ float4 u8_to_f4(ushort4 uu) {
    U8 c;
    c.u = uu;
    float2 f01 = __half22float2(c.h[0]);
    float2 f23 = __half22float2(c.h[1]);
    return make_float4(f01.x, f01.y, f23.x, f23.y);
}

__device__ __forceinline__ ushort4 f4_to_u8(float4 v) {
    U8 c;
    c.h[0] = __floats2half2_rn(v.x, v.y);
    c.h[1] = __floats2half2_rn(v.z, v.w);
    return c.u;
}

// async global->LDS, 16B per lane (dest = wave-uniform base + lane*16)
__device__ __forceinline__ void gload_lds16(const unsigned short* g, unsigned short* l) {
    __builtin_amdgcn_global_load_lds(
        (const __attribute__((address_space(1))) unsigned int*)g,
        (__attribute__((address_space(3))) unsigned int*)l,
        16, 0, 0);
}

// int64-vs-int32 edge layout probe (values < 2^31 => odd words zero)
__device__ __forceinline__ int detect64(const int* __restrict__ e) {
    int ok = 1;
    for (int k = 1; k < 64; k += 2) ok &= (e[k] == 0);
    return ok;
}

// ---------------------------------------------------------------------------
// P1: per-block bucket histogram -> plain writes to base[block][bucket];
// spare lanes also do the weight transpose+cast (fused prep_weights)
// ---------------------------------------------------------------------------
__global__ __launch_bounds__(256) void bucket_hist(const int* __restrict__ e,
                                                   int* __restrict__ base,
                                                   const float* __restrict__ W1,
                                                   const float* __restrict__ W2,
                                                   const float* __restrict__ W3,
                                                   unsigned short* __restrict__ w1t,
                                                   unsigned short* __restrict__ w2t,
                                                   unsigned short* __restrict__ w3t,
                                                   int E) {
    __shared__ int hist[NBKT];
    const int is64 = detect64(e);
    for (int t = threadIdx.x; t < NBKT; t += 256) hist[t] = 0;
    __syncthreads();
    const int chunk = (E + P1B - 1) / P1B;
    const int b0 = blockIdx.x * chunk;
    const int b1 = min(E, b0 + chunk);
    for (int i = b0 + threadIdx.x; i < b1; i += 256) {
        int d = is64 ? e[2 * (E + i)] : e[E + i];
        atomicAdd(&hist[d >> 7], 1);
    }
    // fused weight prep (grid-stride over 69632 elems)
    for (int i = blockIdx.x * 256 + threadIdx.x; i < 69632; i += P1B * 256) {
        const float* W;
        unsigned short* th;
        int K, M, j;
        if (i < 32768)      { W = W1; th = w1t; K = 128; M = 256; j = i; }
        else if (i < 65536) { W = W2; th = w2t; K = 256; M = 128; j = i - 32768; }
        else                { W = W3; th = w3t; K = 128; M = 32;  j = i - 65536; }
        int k = j / M, m = j % M;
        th[(size_t)m * K + k] = __half_as_ushort(__float2half_rn(W[j]));
    }
    __syncthreads();
    for (int t = threadIdx.x; t < NBKT; t += 256)
        base[blockIdx.x * NBKT + t] = hist[t];
}

// ---------------------------------------------------------------------------
// P2: column prefix over base[P1B][NBKT] (per-block exclusive offsets) +
// bucket exclusive scan -> bstart[0..NBKT]. One block, 512 threads.
// ---------------------------------------------------------------------------
__global__ __launch_bounds__(512) void colsum_scan(int* __restrict__ base,
                                                   int* __restrict__ bstart) {
    __shared__ int s[512];
    const int t = threadIdx.x;
    int total = 0;
    if (t < NBKT) {
        for (int b0 = 0; b0 < P1B; b0 += 8) {
            int v[8];
#pragma unroll
            for (int u = 0; u < 8; ++u) v[u] = base[(size_t)(b0 + u) * NBKT + t];
#pragma unroll
            for (int u = 0; u < 8; ++u) {
                int nv = v[u];
                base[(size_t)(b0 + u) * NBKT + t] = total;
                total += nv;
            }
        }
    }
    s[t] = (t < NBKT) ? total : 0;
    __syncthreads();
    for (int off = 1; off < 512; off <<= 1) {
        int tv = (t >= off) ? s[t - off] : 0;
        __syncthreads();
        s[t] += tv;
        __syncthreads();
    }
    if (t < NBKT) bstart[t] = s[t] - total;
    if (t == 0) bstart[NBKT] = s[511];  // total = E
}

// ---------------------------------------------------------------------------
// P3: scatter packed edges (src u16 | dst_local u7) into bucket-binned order
// ---------------------------------------------------------------------------
__global__ __launch_bounds__(256) void bucket_scatter(const int* __restrict__ e,
                                                      const int* __restrict__ bstart,
                                                      const int* __restrict__ base,
                                                      unsigned* __restrict__ pairs, int E) {
    __shared__ int cur[NBKT];
    const int is64 = detect64(e);
    for (int t = threadIdx.x; t < NBKT; t += 256)
        cur[t] = bstart[t] + base[blockIdx.x * NBKT + t];
    __syncthreads();
    const int chunk = (E + P1B - 1) / P1B;
    const int b0 = blockIdx.x * chunk;
    const int b1 = min(E, b0 + chunk);
    for (int i = b0 + threadIdx.x; i < b1; i += 256) {
        int s = is64 ? e[2 * i] : e[i];
        int d = is64 ? e[2 * (E + i)] : e[E + i];
        int pos = atomicAdd(&cur[d >> 7], 1);
        pairs[pos] = (unsigned)s | ((unsigned)(d & 127) << 16);
    }
}

// ---------------------------------------------------------------------------
// P4: one block per bucket. (1) local deg count + scan -> ninfo{beg,deg}/dinv;
// (2) LDS-cursor scatter src -> contiguous u16 CSR range; (3) fused cast of
// this bucket's x rows to pre-scaled fp16 (x' = dinv ⊙ x).
// ---------------------------------------------------------------------------
__global__ __launch_bounds__(256) void bucket_finalize(const unsigned* __restrict__ pairs,
                                                       const int* __restrict__ bstart,
                                                       const float* __restrict__ x,
                                                       int2* __restrict__ ninfo,
                                                       float* __restrict__ dinv,
                                                       unsigned short* __restrict__ csr,
                                                       unsigned short* __restrict__ xh, int n) {
    __shared__ int ldeg[128];
    __shared__ int lscan[128];
    __shared__ int cur[128];
    __shared__ float sdinv[128];
    const int bkt = blockIdx.x;
    const int s0 = bstart[bkt], s1 = bstart[bkt + 1];
    if (threadIdx.x < 128) ldeg[threadIdx.x] = 0;
    __syncthreads();
    for (int i = s0 + threadIdx.x; i < s1; i += 256)
        atomicAdd(&ldeg[pairs[i] >> 16], 1);
    __syncthreads();
    if (threadIdx.x < 128) lscan[threadIdx.x] = ldeg[threadIdx.x];
    __syncthreads();
    for (int off = 1; off < 128; off <<= 1) {
        int v = 0;
        if (threadIdx.x < 128 && threadIdx.x >= off) v = lscan[threadIdx.x - off];
        __syncthreads();
        if (threadIdx.x < 128) lscan[threadIdx.x] += v;
        __syncthreads();
    }
    if (threadIdx.x < 128) {
        int node = (bkt << 7) + threadIdx.x;
        int exc = s0 + lscan[threadIdx.x] - ldeg[threadIdx.x];
        cur[threadIdx.x] = exc;
        float di = rsqrtf((float)(ldeg[threadIdx.x] + 1));  // +1 self-loop
        sdinv[threadIdx.x] = di;
        if (node < n) {
            ninfo[node] = make_int2(exc, ldeg[threadIdx.x]);
            dinv[node] = di;
        }
    }
    __syncthreads();
    // csr scatter (u16 src)
    for (int i = s0 + threadIdx.x; i < s1; i += 256) {
        unsigned pr = pairs[i];
        int pos = atomicAdd(&cur[pr >> 16], 1);
        csr[pos] = (unsigned short)(pr & 0xFFFFu);
    }
    // fused cast: x rows of this bucket -> pre-scaled fp16 (linear, coalesced)
    for (int idx = threadIdx.x; idx < 128 * 32; idx += 256) {
        int ln = idx >> 5;         // local node
        int c4 = idx & 31;         // float4 chunk within row (128 feats)
        int node = (bkt << 7) + ln;
        if (node < n) {
            float4 v = ((const float4*)x)[(size_t)node * 32 + c4];
            float s = sdinv[ln];
            v.x *= s; v.y *= s; v.z *= s; v.w *= s;
            ((ushort4*)xh)[(size_t)node * 32 + c4] = f4_to_u8(v);
        }
    }
}

// ---------------------------------------------------------------------------
// FUSED layer-1+2 GEMM: per 128-row tile,
//   h1 = relu(agg0 @ W1 + b1)   [128 x 256]  (kept in LDS, never hits HBM)
//   h2' = dinv ⊙ (h1 @ W2)      [128 x 128]  (fp16 out)
// ---------------------------------------------------------------------------
__global__ __launch_bounds__(256) void gemm12(
    const unsigned short* __restrict__ A,     // agg0 [N][128] fp16
    const unsigned short* __restrict__ W1t,   // [256][128] fp16
    const unsigned short* __restrict__ W2t,   // [128][256] fp16
    const float* __restrict__ b1,
    const float* __restrict__ dinv,
    unsigned short* __restrict__ H2,          // [N][128] fp16 (scaled)
    int N) {
    __shared__ unsigned short sA[128][128];   // 32KB, swizzled chunks
    __shared__ unsigned short sW[128][128];   // 32KB, swizzled, reused 4x
    __shared__ unsigned short sH[128][136];   // 34.8KB, padded (16B-aligned rows)

    const int tid = threadIdx.x;
    const int lane = tid & 63;
    const int w = tid >> 6;
    const int wr = w >> 1, wc = w & 1;        // 2x2 waves over 128x128
    const int row0 = blockIdx.x * 128;
    const int rsel = lane & 15;
    const int cq = lane >> 4;                 // 0..3

    // stage A tile (rows x K=128): 2048 16B-chunks, slot s holds chunk (s&8)|((s^r)&7)
#pragma unroll
    for (int b = 0; b < 2048; b += 256) {
        int idx = b + tid;
        int r = idx >> 4, s = idx & 15;
        int gr = row0 + r;
        int sp = (s & 8) | ((s ^ r) & 7);
        if (gr < N) gload_lds16(&A[(size_t)gr * 128 + sp * 8], &sA[0][0] + idx * 8);
        // rows >= N: stale LDS; those output rows are never stored
    }

    f32x4 acc2[4][4];
#pragma unroll
    for (int m = 0; m < 4; ++m)
#pragma unroll
        for (int nn = 0; nn < 4; ++nn) {
            f32x4 z = {0.f, 0.f, 0.f, 0.f};
            acc2[m][nn] = z;
        }

    for (int half = 0; half < 2; ++half) {
        __syncthreads();  // drains A-stage (half 0) / prior acc2 reads of sW (half 1)
        // stage W1 half: h1-cols half*128..+127, K=128
#pragma unroll
        for (int b = 0; b < 2048; b += 256) {
            int idx = b + tid;
            int r = idx >> 4, s = idx & 15;
            int sp = (s & 8) | ((s ^ r) & 7);
            gload_lds16(&W1t[(size_t)(half * 128 + r) * 128 + sp * 8], &sW[0][0] + idx * 8);
        }
        __syncthreads();

        // acc1 = sA @ sW^T   (output 128x128, K=128)
        f32x4 acc1[4][4];
#pragma unroll
        for (int m = 0; m < 4; ++m)
#pragma unroll
            for (int nn = 0; nn < 4; ++nn) {
                f32x4 z = {0.f, 0.f, 0.f, 0.f};
                acc1[m][nn] = z;
            }
#pragma unroll
        for (int ks = 0; ks < 4; ++ks) {
            half8v af[4], wf[4];
            int c = ks * 4 + cq;
#pragma unroll
            for (int m = 0; m < 4; ++m) {
                int rr = wr * 64 + m * 16 + rsel;
                int cp = (c & 8) | ((c ^ rr) & 7);
                af[m] = *(const half8v*)&sA[rr][cp * 8];
            }
#pragma unroll
            for (int nn = 0; nn < 4; ++nn) {
                int rr = wc * 64 + nn * 16 + rsel;
                int cp = (c & 8) | ((c ^ rr) & 7);
                wf[nn] = *(const half8v*)&sW[rr][cp * 8];
            }
#pragma unroll
            for (int m = 0; m < 4; ++m)
#pragma unroll
                for (int nn = 0; nn < 4; ++nn)
                    acc1[m][nn] = __builtin_amdgcn_mfma_f32_16x16x32_f16(af[m], wf[nn], acc1[m][nn], 0, 0, 0);
        }

        // bias+relu -> fp16 -> sH (row-major h1 half)
        float b1v[4];
#pragma unroll
        for (int nn = 0; nn < 4; ++nn)
            b1v[nn] = b1[half * 128 + wc * 64 + nn * 16 + rsel];
#pragma unroll
        for (int m = 0; m < 4; ++m)
#pragma unroll
            for (int nn = 0; nn < 4; ++nn)
#pragma unroll
                for (int r = 0; r < 4; ++r) {
                    int rl = wr * 64 + m * 16 + cq * 4 + r;
                    int cl = wc * 64 + nn * 16 + rsel;
                    float v = fmaxf(acc1[m][nn][r] + b1v[nn], 0.f);
                    sH[rl][cl] = __half_as_ushort(__float2half_rn(v));
                }
        __syncthreads();  // sH complete; safe to overwrite sW

        // stage W2 K-slice: rows (h2 cols) 0..127, K in [half*128, half*128+128)
#pragma unroll
        for (int b = 0; b < 2048; b += 256) {
            int idx = b + tid;
            int r = idx >> 4, s = idx & 15;
            int sp = (s & 8) | ((s ^ r) & 7);
            gload_lds16(&W2t[(size_t)r * 256 + half * 128 + sp * 8], &sW[0][0] + idx * 8);
        }
        __syncthreads();

        // acc2 += sH @ sW^T  (K=128 local)
#pragma unroll
        for (int ks = 0; ks < 4; ++ks) {
            half8v ah[4], wf[4];
            int koff = ks * 32 + cq * 8;
            int c = ks * 4 + cq;
#pragma unroll
            for (int m = 0; m < 4; ++m) {
                int rr = wr * 64 + m * 16 + rsel;
                ah[m] = *(const half8v*)&sH[rr][koff];
            }
#pragma unroll
            for (int nn = 0; nn < 4; ++nn) {
                int rr = wc * 64 + nn * 16 + rsel;
                int cp = (c & 8) | ((c ^ rr) & 7);
                wf[nn] = *(const half8v*)&sW[rr][cp * 8];
            }
#pragma unroll
            for (int m = 0; m < 4; ++m)
#pragma unroll
                for (int nn = 0; nn < 4; ++nn)
                    acc2[m][nn] = __builtin_amdgcn_mfma_f32_16x16x32_f16(ah[m], wf[nn], acc2[m][nn], 0, 0, 0);
        }
    }

    // epilogue: h2' = dinv ⊙ acc2, fp16 out
#pragma unroll
    for (int m = 0; m < 4; ++m)
#pragma unroll
        for (int r = 0; r < 4; ++r) {
            int row = row0 + wr * 64 + m * 16 + cq * 4 + r;
            if (row >= N) continue;
            float rs = dinv[row];
#pragma unroll
            for (int nn = 0; nn < 4; ++nn) {
                int col = wc * 64 + nn * 16 + rsel;
                H2[(size_t)row * 128 + col] =
                    __half_as_ushort(__float2half_rn(acc2[m][nn][r] * rs));
            }
        }
}

// ---------------------------------------------------------------------------
// fp16 MFMA GEMM (single): C[N,M] = A[N,K](fp16) @ W[K,M](fp16, transposed),
// KS=64, gload_lds + chunk-XOR swizzle. OUTF16 / SCALE as before.
// ---------------------------------------------------------------------------
template <int BM, int BN, int WM, int WN, bool BIAS, bool RELU, bool OUTF16, bool SCALE>
__global__ __launch_bounds__(256) void gemm_f16(
    const unsigned short* __restrict__ A,
    const unsigned short* __restrict__ Wt,
    const float* __restrict__ bias, const float* __restrict__ dscale,
    float* __restrict__ Cf, unsigned short* __restrict__ Ch,
    int N, int K, int M) {
    constexpr int KS = 64;
    constexpr int WTM = BM / WM;
    constexpr int WTN = BN / WN;
    constexpr int FM = WTM / 16;
    constexpr int FN = WTN / 16;
    constexpr int ACH = BM * 8;
    constexpr int WCH = BN * 8;
    __shared__ unsigned short sA[BM][KS], sW[BN][KS];

    const int tid = threadIdx.x;
    const int lane = tid & 63;
    const int w = tid >> 6;
    const int wr = w / WN, wc = w % WN;
    const int row0 = blockIdx.y * BM;
    const int col0 = blockIdx.x * BN;

    f32x4 acc[FM][FN];
#pragma unroll
    for (int m = 0; m < FM; ++m)
#pragma unroll
        for (int nn = 0; nn < FN; ++nn) {
            f32x4 z = {0.f, 0.f, 0.f, 0.f};
            acc[m][nn] = z;
        }

    for (int k0 = 0; k0 < K; k0 += KS) {
#pragma unroll
        for (int b = 0; b < ACH; b += 256) {
            int idx = b + tid;
            int r = idx >> 3, s = idx & 7;
            int gr = row0 + r;
            int sp = s ^ (r & 7);
            if (gr < N)
                gload_lds16(&A[(size_t)gr * K + k0 + sp * 8], &sA[0][0] + idx * 8);
        }
#pragma unroll
        for (int b = 0; b < WCH; b += 256) {
            int idx = b + tid;
            int r = idx >> 3, s = idx & 7;
            int gc = col0 + r;
            int sp = s ^ (r & 7);
            gload_lds16(&Wt[(size_t)gc * K + k0 + sp * 8], &sW[0][0] + idx * 8);
        }
        __syncthreads();

        half8v af[FM][2], wf[FN][2];
        const int rsel = lane & 15;
        const int cb = lane >> 4;
#pragma unroll
        for (int m = 0; m < FM; ++m) {
            int rr = wr * WTM + m * 16 + rsel;
            af[m][0] = *(const half8v*)&sA[rr][((cb) ^ (rr & 7)) * 8];
            af[m][1] = *(const half8v*)&sA[rr][((cb + 4) ^ (rr & 7)) * 8];
        }
#pragma unroll
        for (int nn = 0; nn < FN; ++nn) {
            int rr = wc * WTN + nn * 16 + rsel;
            wf[nn][0] = *(const half8v*)&sW[rr][((cb) ^ (rr & 7)) * 8];
            wf[nn][1] = *(const half8v*)&sW[rr][((cb + 4) ^ (rr & 7)) * 8];
        }
#pragma unroll
        for (int m = 0; m < FM; ++m)
#pragma unroll
            for (int nn = 0; nn < FN; ++nn) {
                acc[m][nn] = __builtin_amdgcn_mfma_f32_16x16x32_f16(af[m][0], wf[nn][0], acc[m][nn], 0, 0, 0);
                acc[m][nn] = __builtin_amdgcn_mfma_f32_16x16x32_f16(af[m][1], wf[nn][1], acc[m][nn], 0, 0, 0);
            }
        __syncthreads();
    }

#pragma unroll
    for (int m = 0; m < FM; ++m) {
#pragma unroll
        for (int r = 0; r < 4; ++r) {
            int row = row0 + wr * WTM + m * 16 + (lane >> 4) * 4 + r;
            if (row >= N) continue;
            float rs = SCALE ? dscale[row] : 1.f;
#pragma unroll
            for (int nn = 0; nn < FN; ++nn) {
                int col = col0 + wc * WTN + nn * 16 + (lane & 15);
                float v = acc[m][nn][r];
                if (BIAS) v += bias[col];
                if (RELU) v = fmaxf(v, 0.f);
                if (SCALE) v *= rs;
                if constexpr (OUTF16) {
                    Ch[(size_t)row * M + col] = __half_as_ushort(__float2half_rn(v));
                } else {
                    Cf[(size_t)row * M + col] = v;
                }
            }
        }
    }
}

// ---------------------------------------------------------------------------
// CSR aggregation over PRE-SCALED fp16 table h' = dinv ⊙ h:
// out[d] = dinv[d] * (h'[d] + Σ h'[s]) + bias
// 8-deep clamped batched gathers (low VGPR -> high occupancy; latency-bound)
// ---------------------------------------------------------------------------
__device__ __forceinline__ float4 add4(float4 v, float4 a) {
    a.x += v.x; a.y += v.y; a.z += v.z; a.w += v.w;
    return a;
}

template <int F, int NPB, bool BIAS, bool RELU, bool OUTF16>
__global__ __launch_bounds__((F / 4) * NPB) void agg4h(
    const unsigned short* __restrict__ h, const int2* __restrict__ ninfo,
    const unsigned short* __restrict__ csr,
    const float* __restrict__ dinv, const float* __restrict__ bias,
    float* __restrict__ outf, unsigned short* __restrict__ outh, int n) {
    constexpr int L = F / 4;
    const int local = threadIdx.x / L;
    const int lane = threadIdx.x % L;
    const int node = blockIdx.x * NPB + local;
    if (node >= n) return;

    const ushort4* __restrict__ h4 = (const ushort4*)h;
    const float di = dinv[node];
    const int2 info = ninfo[node];
    const int beg = info.x;
    const int num = info.y;

    float4 acc = u8_to_f4(h4[(size_t)node * L + lane]);  // self term h'[d]

    for (int e = 0; e < num; e += 8) {
        int c[8];
        ushort4 raw[8];
#pragma unroll
        for (int u = 0; u < 8; ++u) {
            int idx = min(e + u, num - 1);           // clamp: dup loads are L1-hot
            c[u] = csr[beg + idx];
        }
#pragma unroll
        for (int u = 0; u < 8; ++u) raw[u] = h4[(size_t)c[u] * L + lane];
#pragma unroll
        for (int u = 0; u < 8; ++u) {
            float4 v = u8_to_f4(raw[u]);
            if (e + u < num) acc = add4(v, acc);     // predicated; order unchanged
        }
    }
    acc.x *= di; acc.y *= di; acc.z *= di; acc.w *= di;
    if (BIAS) {
        const float4 b = ((const float4*)bias)[lane];
        acc.x += b.x; acc.y += b.y; acc.z += b.z; acc.w += b.w;
    }
    if (RELU) {
        acc.x = fmaxf(acc.x, 0.f); acc.y = fmaxf(acc.y, 0.f);
        acc.z = fmaxf(acc.z, 0.f); acc.w = fmaxf(acc.w, 0.f);
    }
    if constexpr (OUTF16) {
        ((ushort4*)outh)[(size_t)node * L + lane] = f4_to_u8(acc);
    } else {
        ((float4*)outf)[(size_t)node * L + lane] = acc;
    }
}

// ---------------------------------------------------------------------------
extern "C" void kernel_launch(void* const* d_in, const int* in_sizes, int n_in,
                              void* d_out, int out_size, void* d_ws, size_t ws_size,
                              hipStream_t stream) {
    const float* x   = (const float*)d_in[0];
    const int*   eix = (const int*)d_in[1];
    const float* W1  = (const float*)d_in[2];
    const float* b1  = (const float*)d_in[3];
    const float* W2  = (const float*)d_in[4];
    const float* b2  = (const float*)d_in[5];
    const float* W3  = (const float*)d_in[6];
    const float* b3  = (const float*)d_in[7];
    float* out = (float*)d_out;

    const int n = NN, E = NE;

    char* p = (char*)d_ws;
    auto alloc = [&](size_t bytes) { void* r = (void*)p; p += align_up(bytes, 256); return r; };
    int2*  ninfo     = (int2*)alloc((size_t)n * 8);
    float* dinv      = (float*)alloc((size_t)n * 4);
    int*   bstart    = (int*)alloc((size_t)(NBKT + 1) * 4);
    int*   base      = (int*)alloc((size_t)P1B * NBKT * 4);
    unsigned* pairs  = (unsigned*)alloc((size_t)E * 4);
    unsigned short* csr = (unsigned short*)alloc((size_t)E * 2);
    unsigned short* w1t = (unsigned short*)alloc((size_t)128 * 256 * 2);
    unsigned short* w2t = (unsigned short*)alloc((size_t)256 * 128 * 2);
    unsigned short* w3t = (unsigned short*)alloc((size_t)128 * 32 * 2);
    unsigned short* xh   = (unsigned short*)alloc((size_t)n * 128 * 2);  // x'  fp16
    unsigned short* agg0 = (unsigned short*)alloc((size_t)n * 128 * 2);  // agg0 fp16
    unsigned short* h2s  = (unsigned short*)alloc((size_t)n * 128 * 2);  // h2' fp16 (scaled)
    unsigned short* x3   = (unsigned short*)alloc((size_t)n * 128 * 2);  // x3  fp16
    unsigned short* h3s  = (unsigned short*)alloc((size_t)n * 32 * 2);   // h3' fp16 (scaled)
    (void)ws_size; (void)in_sizes; (void)n_in; (void)out_size;

    // ---- CSR build: hist(+weight prep) -> colsum+scan -> scatter ->
    //      finalize(+fused x cast)
    bucket_hist<<<P1B, 256, 0, stream>>>(eix, base, W1, W2, W3, w1t, w2t, w3t, E);
    colsum_scan<<<1, 512, 0, stream>>>(base, bstart);
    bucket_scatter<<<P1B, 256, 0, stream>>>(eix, bstart, base, pairs, E);
    bucket_finalize<<<NBKT, 256, 0, stream>>>(pairs, bstart, x, ninfo, dinv, csr, xh, n);

    const int RB = (n + 127) / 128;  // 391 row blocks

    // ---- layer 1 agg: agg0 = A_norm-gather(x') (fp16)
    agg4h<128, 8, false, false, true><<<(n + 7) / 8, 256, 0, stream>>>(
        xh, ninfo, csr, dinv, nullptr, nullptr, agg0, n);

    // ---- FUSED gemm1+gemm2: h2' = dinv ⊙ (relu(agg0 @ W1 + b1) @ W2) (fp16)
    gemm12<<<RB, 256, 0, stream>>>(agg0, w1t, w2t, b1, dinv, h2s, n);

    // ---- layer 2 agg: x3 = relu(agg(h2') + b2) (fp16)
    agg4h<128, 8, true, true, true><<<(n + 7) / 8, 256, 0, stream>>>(
        h2s, ninfo, csr, dinv, b2, nullptr, x3, n);

    // ---- layer 3: h3' = dinv ⊙ (x3 @ W3) (fp16); out = agg(h3') + b3 (f32)
    gemm_f16<128, 32, 4, 1, false, false, true, true><<<dim3(1, RB), 256, 0, stream>>>(
        x3, w3t, nullptr, dinv, nullptr, h3s, n, 128, 32);
    agg4h<32, 32, true, false, false><<<(n + 31) / 32, 256, 0, stream>>>(
        h3s, ninfo, csr, dinv, b3, out, nullptr, n);
}

// Round 15
// 151.071 us; speedup vs baseline: 1.3328x; 1.0406x over previous
//
#include <hip/hip_runtime.h>
#include <hip/hip_fp16.h>

#define NN 50000
#define NE 800000
#define NBKT 391          // ceil(50000/128) buckets of 128 nodes
#define P1B 256           // blocks in hist/scatter passes

typedef __attribute__((ext_vector_type(8))) _Float16 half8v;  // 8 fp16 in 4 VGPRs
typedef __attribute__((ext_vector_type(4))) float f32x4;

static inline size_t align_up(size_t x, size_t a) { return (x + a - 1) & ~(a - 1); }

union U8 {
    ushort4 u;
    __half2 h[2];
};

__device__ __forceinline__ float4 u8_to_f4(ushort4 uu) {
    U8 c;
    c.u = uu;
    float2 f01 = __half22float2(c.h[0]);
    float2 f23 = __half22float2(c.h[1]);
    return make_float4(f01.x, f01.y, f23.x, f23.y);
}

__device__ __forceinline__ ushort4 f4_to_u8(float4 v) {
    U8 c;
    c.h[0] = __floats2half2_rn(v.x, v.y);
    c.h[1] = __floats2half2_rn(v.z, v.w);
    return c.u;
}

__device__ __forceinline__ float4 add4(float4 v, float4 a) {
    a.x += v.x; a.y += v.y; a.z += v.z; a.w += v.w;
    return a;
}

// async global->LDS, 16B per lane (dest = wave-uniform base + lane*16)
__device__ __forceinline__ void gload_lds16(const unsigned short* g, unsigned short* l) {
    __builtin_amdgcn_global_load_lds(
        (const __attribute__((address_space(1))) unsigned int*)g,
        (__attribute__((address_space(3))) unsigned int*)l,
        16, 0, 0);
}

// int64-vs-int32 edge layout probe (values < 2^31 => odd words zero)
__device__ __forceinline__ int detect64(const int* __restrict__ e) {
    int ok = 1;
    for (int k = 1; k < 64; k += 2) ok &= (e[k] == 0);
    return ok;
}

// ---------------------------------------------------------------------------
// P1: per-block bucket histogram -> plain writes to base[block][bucket];
// spare lanes also do the weight transpose+cast (fused prep_weights)
// ---------------------------------------------------------------------------
__global__ __launch_bounds__(256) void bucket_hist(const int* __restrict__ e,
                                                   int* __restrict__ base,
                                                   const float* __restrict__ W1,
                                                   const float* __restrict__ W2,
                                                   const float* __restrict__ W3,
                                                   unsigned short* __restrict__ w1t,
                                                   unsigned short* __restrict__ w2t,
                                                   unsigned short* __restrict__ w3t,
                                                   int E) {
    __shared__ int hist[NBKT];
    const int is64 = detect64(e);
    for (int t = threadIdx.x; t < NBKT; t += 256) hist[t] = 0;
    __syncthreads();
    const int chunk = (E + P1B - 1) / P1B;
    const int b0 = blockIdx.x * chunk;
    const int b1 = min(E, b0 + chunk);
    for (int i = b0 + threadIdx.x; i < b1; i += 256) {
        int d = is64 ? e[2 * (E + i)] : e[E + i];
        atomicAdd(&hist[d >> 7], 1);
    }
    // fused weight prep (grid-stride over 69632 elems)
    for (int i = blockIdx.x * 256 + threadIdx.x; i < 69632; i += P1B * 256) {
        const float* W;
        unsigned short* th;
        int K, M, j;
        if (i < 32768)      { W = W1; th = w1t; K = 128; M = 256; j = i; }
        else if (i < 65536) { W = W2; th = w2t; K = 256; M = 128; j = i - 32768; }
        else                { W = W3; th = w3t; K = 128; M = 32;  j = i - 65536; }
        int k = j / M, m = j % M;
        th[(size_t)m * K + k] = __half_as_ushort(__float2half_rn(W[j]));
    }
    __syncthreads();
    for (int t = threadIdx.x; t < NBKT; t += 256)
        base[blockIdx.x * NBKT + t] = hist[t];
}

// ---------------------------------------------------------------------------
// P2: column prefix over base[P1B][NBKT] (per-block exclusive offsets) +
// bucket exclusive scan -> bstart[0..NBKT]. One block, 512 threads.
// ---------------------------------------------------------------------------
__global__ __launch_bounds__(512) void colsum_scan(int* __restrict__ base,
                                                   int* __restrict__ bstart) {
    __shared__ int s[512];
    const int t = threadIdx.x;
    int total = 0;
    if (t < NBKT) {
        for (int b0 = 0; b0 < P1B; b0 += 8) {
            int v[8];
#pragma unroll
            for (int u = 0; u < 8; ++u) v[u] = base[(size_t)(b0 + u) * NBKT + t];
#pragma unroll
            for (int u = 0; u < 8; ++u) {
                int nv = v[u];
                base[(size_t)(b0 + u) * NBKT + t] = total;
                total += nv;
            }
        }
    }
    s[t] = (t < NBKT) ? total : 0;
    __syncthreads();
    for (int off = 1; off < 512; off <<= 1) {
        int tv = (t >= off) ? s[t - off] : 0;
        __syncthreads();
        s[t] += tv;
        __syncthreads();
    }
    if (t < NBKT) bstart[t] = s[t] - total;
    if (t == 0) bstart[NBKT] = s[511];  // total = E
}

// ---------------------------------------------------------------------------
// P3: scatter packed edges (src u16 | dst_local u7) into bucket-binned order
// ---------------------------------------------------------------------------
__global__ __launch_bounds__(256) void bucket_scatter(const int* __restrict__ e,
                                                      const int* __restrict__ bstart,
                                                      const int* __restrict__ base,
                                                      unsigned* __restrict__ pairs, int E) {
    __shared__ int cur[NBKT];
    const int is64 = detect64(e);
    for (int t = threadIdx.x; t < NBKT; t += 256)
        cur[t] = bstart[t] + base[blockIdx.x * NBKT + t];
    __syncthreads();
    const int chunk = (E + P1B - 1) / P1B;
    const int b0 = blockIdx.x * chunk;
    const int b1 = min(E, b0 + chunk);
    for (int i = b0 + threadIdx.x; i < b1; i += 256) {
        int s = is64 ? e[2 * i] : e[i];
        int d = is64 ? e[2 * (E + i)] : e[E + i];
        int pos = atomicAdd(&cur[d >> 7], 1);
        pairs[pos] = (unsigned)s | ((unsigned)(d & 127) << 16);
    }
}

// ---------------------------------------------------------------------------
// P4: one block per bucket. (1) local deg count + scan -> ninfo{beg,deg}/dinv;
// (2) LDS-cursor scatter src -> contiguous u16 CSR range; (3) fused cast of
// this bucket's x rows to pre-scaled fp16 (x' = dinv ⊙ x).
// ---------------------------------------------------------------------------
__global__ __launch_bounds__(256) void bucket_finalize(const unsigned* __restrict__ pairs,
                                                       const int* __restrict__ bstart,
                                                       const float* __restrict__ x,
                                                       int2* __restrict__ ninfo,
                                                       float* __restrict__ dinv,
                                                       unsigned short* __restrict__ csr,
                                                       unsigned short* __restrict__ xh, int n) {
    __shared__ int ldeg[128];
    __shared__ int lscan[128];
    __shared__ int cur[128];
    __shared__ float sdinv[128];
    const int bkt = blockIdx.x;
    const int s0 = bstart[bkt], s1 = bstart[bkt + 1];
    if (threadIdx.x < 128) ldeg[threadIdx.x] = 0;
    __syncthreads();
    for (int i = s0 + threadIdx.x; i < s1; i += 256)
        atomicAdd(&ldeg[pairs[i] >> 16], 1);
    __syncthreads();
    if (threadIdx.x < 128) lscan[threadIdx.x] = ldeg[threadIdx.x];
    __syncthreads();
    for (int off = 1; off < 128; off <<= 1) {
        int v = 0;
        if (threadIdx.x < 128 && threadIdx.x >= off) v = lscan[threadIdx.x - off];
        __syncthreads();
        if (threadIdx.x < 128) lscan[threadIdx.x] += v;
        __syncthreads();
    }
    if (threadIdx.x < 128) {
        int node = (bkt << 7) + threadIdx.x;
        int exc = s0 + lscan[threadIdx.x] - ldeg[threadIdx.x];
        cur[threadIdx.x] = exc;
        float di = rsqrtf((float)(ldeg[threadIdx.x] + 1));  // +1 self-loop
        sdinv[threadIdx.x] = di;
        if (node < n) {
            ninfo[node] = make_int2(exc, ldeg[threadIdx.x]);
            dinv[node] = di;
        }
    }
    __syncthreads();
    // csr scatter (u16 src)
    for (int i = s0 + threadIdx.x; i < s1; i += 256) {
        unsigned pr = pairs[i];
        int pos = atomicAdd(&cur[pr >> 16], 1);
        csr[pos] = (unsigned short)(pr & 0xFFFFu);
    }
    // fused cast: x rows of this bucket -> pre-scaled fp16 (linear, coalesced)
    for (int idx = threadIdx.x; idx < 128 * 32; idx += 256) {
        int ln = idx >> 5;         // local node
        int c4 = idx & 31;         // float4 chunk within row (128 feats)
        int node = (bkt << 7) + ln;
        if (node < n) {
            float4 v = ((const float4*)x)[(size_t)node * 32 + c4];
            float s = sdinv[ln];
            v.x *= s; v.y *= s; v.z *= s; v.w *= s;
            ((ushort4*)xh)[(size_t)node * 32 + c4] = f4_to_u8(v);
        }
    }
}

// ---------------------------------------------------------------------------
// FUSED layer-1+2 GEMM: per 128-row tile,
//   h1 = relu(agg0 @ W1 + b1)   [128 x 256]  (kept in LDS, never hits HBM)
//   h2' = dinv ⊙ (h1 @ W2)      [128 x 128]  (fp16 out)
// ---------------------------------------------------------------------------
__global__ __launch_bounds__(256) void gemm12(
    const unsigned short* __restrict__ A,     // agg0 [N][128] fp16
    const unsigned short* __restrict__ W1t,   // [256][128] fp16
    const unsigned short* __restrict__ W2t,   // [128][256] fp16
    const float* __restrict__ b1,
    const float* __restrict__ dinv,
    unsigned short* __restrict__ H2,          // [N][128] fp16 (scaled)
    int N) {
    __shared__ unsigned short sA[128][128];   // 32KB, swizzled chunks
    __shared__ unsigned short sW[128][128];   // 32KB, swizzled, reused 4x
    __shared__ unsigned short sH[128][136];   // 34.8KB, padded (16B-aligned rows)

    const int tid = threadIdx.x;
    const int lane = tid & 63;
    const int w = tid >> 6;
    const int wr = w >> 1, wc = w & 1;        // 2x2 waves over 128x128
    const int row0 = blockIdx.x * 128;
    const int rsel = lane & 15;
    const int cq = lane >> 4;                 // 0..3

    // stage A tile (rows x K=128): 2048 16B-chunks, slot s holds chunk (s&8)|((s^r)&7)
#pragma unroll
    for (int b = 0; b < 2048; b += 256) {
        int idx = b + tid;
        int r = idx >> 4, s = idx & 15;
        int gr = row0 + r;
        int sp = (s & 8) | ((s ^ r) & 7);
        if (gr < N) gload_lds16(&A[(size_t)gr * 128 + sp * 8], &sA[0][0] + idx * 8);
        // rows >= N: stale LDS; those output rows are never stored
    }

    f32x4 acc2[4][4];
#pragma unroll
    for (int m = 0; m < 4; ++m)
#pragma unroll
        for (int nn = 0; nn < 4; ++nn) {
            f32x4 z = {0.f, 0.f, 0.f, 0.f};
            acc2[m][nn] = z;
        }

    for (int half = 0; half < 2; ++half) {
        __syncthreads();  // drains A-stage (half 0) / prior acc2 reads of sW (half 1)
        // stage W1 half: h1-cols half*128..+127, K=128
#pragma unroll
        for (int b = 0; b < 2048; b += 256) {
            int idx = b + tid;
            int r = idx >> 4, s = idx & 15;
            int sp = (s & 8) | ((s ^ r) & 7);
            gload_lds16(&W1t[(size_t)(half * 128 + r) * 128 + sp * 8], &sW[0][0] + idx * 8);
        }
        __syncthreads();

        // acc1 = sA @ sW^T   (output 128x128, K=128)
        f32x4 acc1[4][4];
#pragma unroll
        for (int m = 0; m < 4; ++m)
#pragma unroll
            for (int nn = 0; nn < 4; ++nn) {
                f32x4 z = {0.f, 0.f, 0.f, 0.f};
                acc1[m][nn] = z;
            }
#pragma unroll
        for (int ks = 0; ks < 4; ++ks) {
            half8v af[4], wf[4];
            int c = ks * 4 + cq;
#pragma unroll
            for (int m = 0; m < 4; ++m) {
                int rr = wr * 64 + m * 16 + rsel;
                int cp = (c & 8) | ((c ^ rr) & 7);
                af[m] = *(const half8v*)&sA[rr][cp * 8];
            }
#pragma unroll
            for (int nn = 0; nn < 4; ++nn) {
                int rr = wc * 64 + nn * 16 + rsel;
                int cp = (c & 8) | ((c ^ rr) & 7);
                wf[nn] = *(const half8v*)&sW[rr][cp * 8];
            }
#pragma unroll
            for (int m = 0; m < 4; ++m)
#pragma unroll
                for (int nn = 0; nn < 4; ++nn)
                    acc1[m][nn] = __builtin_amdgcn_mfma_f32_16x16x32_f16(af[m], wf[nn], acc1[m][nn], 0, 0, 0);
        }

        // bias+relu -> fp16 -> sH (row-major h1 half)
        float b1v[4];
#pragma unroll
        for (int nn = 0; nn < 4; ++nn)
            b1v[nn] = b1[half * 128 + wc * 64 + nn * 16 + rsel];
#pragma unroll
        for (int m = 0; m < 4; ++m)
#pragma unroll
            for (int nn = 0; nn < 4; ++nn)
#pragma unroll
                for (int r = 0; r < 4; ++r) {
                    int rl = wr * 64 + m * 16 + cq * 4 + r;
                    int cl = wc * 64 + nn * 16 + rsel;
                    float v = fmaxf(acc1[m][nn][r] + b1v[nn], 0.f);
                    sH[rl][cl] = __half_as_ushort(__float2half_rn(v));
                }
        __syncthreads();  // sH complete; safe to overwrite sW

        // stage W2 K-slice: rows (h2 cols) 0..127, K in [half*128, half*128+128)
#pragma unroll
        for (int b = 0; b < 2048; b += 256) {
            int idx = b + tid;
            int r = idx >> 4, s = idx & 15;
            int sp = (s & 8) | ((s ^ r) & 7);
            gload_lds16(&W2t[(size_t)r * 256 + half * 128 + sp * 8], &sW[0][0] + idx * 8);
        }
        __syncthreads();

        // acc2 += sH @ sW^T  (K=128 local)
#pragma unroll
        for (int ks = 0; ks < 4; ++ks) {
            half8v ah[4], wf[4];
            int koff = ks * 32 + cq * 8;
            int c = ks * 4 + cq;
#pragma unroll
            for (int m = 0; m < 4; ++m) {
                int rr = wr * 64 + m * 16 + rsel;
                ah[m] = *(const half8v*)&sH[rr][koff];
            }
#pragma unroll
            for (int nn = 0; nn < 4; ++nn) {
                int rr = wc * 64 + nn * 16 + rsel;
                int cp = (c & 8) | ((c ^ rr) & 7);
                wf[nn] = *(const half8v*)&sW[rr][cp * 8];
            }
#pragma unroll
            for (int m = 0; m < 4; ++m)
#pragma unroll
                for (int nn = 0; nn < 4; ++nn)
                    acc2[m][nn] = __builtin_amdgcn_mfma_f32_16x16x32_f16(ah[m], wf[nn], acc2[m][nn], 0, 0, 0);
        }
    }

    // epilogue: h2' = dinv ⊙ acc2, fp16 out
#pragma unroll
    for (int m = 0; m < 4; ++m)
#pragma unroll
        for (int r = 0; r < 4; ++r) {
            int row = row0 + wr * 64 + m * 16 + cq * 4 + r;
            if (row >= N) continue;
            float rs = dinv[row];
#pragma unroll
            for (int nn = 0; nn < 4; ++nn) {
                int col = wc * 64 + nn * 16 + rsel;
                H2[(size_t)row * 128 + col] =
                    __half_as_ushort(__float2half_rn(acc2[m][nn][r] * rs));
            }
        }
}

// ---------------------------------------------------------------------------
// fp16 MFMA GEMM (single): C[N,M] = A[N,K](fp16) @ W[K,M](fp16, transposed),
// KS=64, gload_lds + chunk-XOR swizzle. OUTF16 / SCALE as before.
// ---------------------------------------------------------------------------
template <int BM, int BN, int WM, int WN, bool BIAS, bool RELU, bool OUTF16, bool SCALE>
__global__ __launch_bounds__(256) void gemm_f16(
    const unsigned short* __restrict__ A,
    const unsigned short* __restrict__ Wt,
    const float* __restrict__ bias, const float* __restrict__ dscale,
    float* __restrict__ Cf, unsigned short* __restrict__ Ch,
    int N, int K, int M) {
    constexpr int KS = 64;
    constexpr int WTM = BM / WM;
    constexpr int WTN = BN / WN;
    constexpr int FM = WTM / 16;
    constexpr int FN = WTN / 16;
    constexpr int ACH = BM * 8;
    constexpr int WCH = BN * 8;
    __shared__ unsigned short sA[BM][KS], sW[BN][KS];

    const int tid = threadIdx.x;
    const int lane = tid & 63;
    const int w = tid >> 6;
    const int wr = w / WN, wc = w % WN;
    const int row0 = blockIdx.y * BM;
    const int col0 = blockIdx.x * BN;

    f32x4 acc[FM][FN];
#pragma unroll
    for (int m = 0; m < FM; ++m)
#pragma unroll
        for (int nn = 0; nn < FN; ++nn) {
            f32x4 z = {0.f, 0.f, 0.f, 0.f};
            acc[m][nn] = z;
        }

    for (int k0 = 0; k0 < K; k0 += KS) {
#pragma unroll
        for (int b = 0; b < ACH; b += 256) {
            int idx = b + tid;
            int r = idx >> 3, s = idx & 7;
            int gr = row0 + r;
            int sp = s ^ (r & 7);
            if (gr < N)
                gload_lds16(&A[(size_t)gr * K + k0 + sp * 8], &sA[0][0] + idx * 8);
        }
#pragma unroll
        for (int b = 0; b < WCH; b += 256) {
            int idx = b + tid;
            int r = idx >> 3, s = idx & 7;
            int gc = col0 + r;
            int sp = s ^ (r & 7);
            gload_lds16(&Wt[(size_t)gc * K + k0 + sp * 8], &sW[0][0] + idx * 8);
        }
        __syncthreads();

        half8v af[FM][2], wf[FN][2];
        const int rsel = lane & 15;
        const int cb = lane >> 4;
#pragma unroll
        for (int m = 0; m < FM; ++m) {
            int rr = wr * WTM + m * 16 + rsel;
            af[m][0] = *(const half8v*)&sA[rr][((cb) ^ (rr & 7)) * 8];
            af[m][1] = *(const half8v*)&sA[rr][((cb + 4) ^ (rr & 7)) * 8];
        }
#pragma unroll
        for (int nn = 0; nn < FN; ++nn) {
            int rr = wc * WTN + nn * 16 + rsel;
            wf[nn][0] = *(const half8v*)&sW[rr][((cb) ^ (rr & 7)) * 8];
            wf[nn][1] = *(const half8v*)&sW[rr][((cb + 4) ^ (rr & 7)) * 8];
        }
#pragma unroll
        for (int m = 0; m < FM; ++m)
#pragma unroll
            for (int nn = 0; nn < FN; ++nn) {
                acc[m][nn] = __builtin_amdgcn_mfma_f32_16x16x32_f16(af[m][0], wf[nn][0], acc[m][nn], 0, 0, 0);
                acc[m][nn] = __builtin_amdgcn_mfma_f32_16x16x32_f16(af[m][1], wf[nn][1], acc[m][nn], 0, 0, 0);
            }
        __syncthreads();
    }

#pragma unroll
    for (int m = 0; m < FM; ++m) {
#pragma unroll
        for (int r = 0; r < 4; ++r) {
            int row = row0 + wr * WTM + m * 16 + (lane >> 4) * 4 + r;
            if (row >= N) continue;
            float rs = SCALE ? dscale[row] : 1.f;
#pragma unroll
            for (int nn = 0; nn < FN; ++nn) {
                int col = col0 + wc * WTN + nn * 16 + (lane & 15);
                float v = acc[m][nn][r];
                if (BIAS) v += bias[col];
                if (RELU) v = fmaxf(v, 0.f);
                if (SCALE) v *= rs;
                if constexpr (OUTF16) {
                    Ch[(size_t)row * M + col] = __half_as_ushort(__float2half_rn(v));
                } else {
                    Cf[(size_t)row * M + col] = v;
                }
            }
        }
    }
}

// ---------------------------------------------------------------------------
// F=128 CSR aggregation, 16 lanes/node x 16B (uint4) loads, 8-deep batch:
// out[d] = dinv[d] * (h'[d] + Σ h'[s]) (+bias, relu), fp16 out.
// Per-feature f32 add order identical to the 8B version (bit-identical).
// ---------------------------------------------------------------------------
template <int NPB, bool BIAS, bool RELU>
__global__ __launch_bounds__(16 * NPB) void agg16h(
    const unsigned short* __restrict__ h, const int2* __restrict__ ninfo,
    const unsigned short* __restrict__ csr,
    const float* __restrict__ dinv, const float* __restrict__ bias,
    unsigned short* __restrict__ outh, int n) {
    const int local = threadIdx.x >> 4;
    const int lane = threadIdx.x & 15;
    const int node = blockIdx.x * NPB + local;
    if (node >= n) return;

    const uint4* __restrict__ h16 = (const uint4*)h;  // 16B chunks; 16 per row
    const float di = dinv[node];
    const int2 info = ninfo[node];
    const int beg = info.x;
    const int num = info.y;

    uint4 self = h16[(size_t)node * 16 + lane];
    float4 accA = u8_to_f4(*(const ushort4*)&self.x);
    float4 accB = u8_to_f4(*(const ushort4*)&self.z);

    for (int e = 0; e < num; e += 8) {
        int c[8];
        uint4 raw[8];
#pragma unroll
        for (int u = 0; u < 8; ++u) {
            int idx = min(e + u, num - 1);           // clamp: dup loads are L1-hot
            c[u] = csr[beg + idx];
        }
#pragma unroll
        for (int u = 0; u < 8; ++u) raw[u] = h16[(size_t)c[u] * 16 + lane];
#pragma unroll
        for (int u = 0; u < 8; ++u) {
            if (e + u < num) {                       // predicated; order unchanged
                accA = add4(u8_to_f4(*(const ushort4*)&raw[u].x), accA);
                accB = add4(u8_to_f4(*(const ushort4*)&raw[u].z), accB);
            }
        }
    }
    accA.x *= di; accA.y *= di; accA.z *= di; accA.w *= di;
    accB.x *= di; accB.y *= di; accB.z *= di; accB.w *= di;
    if (BIAS) {
        const float4* b4 = (const float4*)bias;
        float4 bA = b4[lane * 2], bB = b4[lane * 2 + 1];
        accA.x += bA.x; accA.y += bA.y; accA.z += bA.z; accA.w += bA.w;
        accB.x += bB.x; accB.y += bB.y; accB.z += bB.z; accB.w += bB.w;
    }
    if (RELU) {
        accA.x = fmaxf(accA.x, 0.f); accA.y = fmaxf(accA.y, 0.f);
        accA.z = fmaxf(accA.z, 0.f); accA.w = fmaxf(accA.w, 0.f);
        accB.x = fmaxf(accB.x, 0.f); accB.y = fmaxf(accB.y, 0.f);
        accB.z = fmaxf(accB.z, 0.f); accB.w = fmaxf(accB.w, 0.f);
    }
    uint4 o;
    *(ushort4*)&o.x = f4_to_u8(accA);
    *(ushort4*)&o.z = f4_to_u8(accB);
    ((uint4*)outh)[(size_t)node * 16 + lane] = o;
}

// ---------------------------------------------------------------------------
// Generic CSR aggregation (used for final F=32 agg, f32 out), 8-deep batch
// ---------------------------------------------------------------------------
template <int F, int NPB, bool BIAS, bool RELU, bool OUTF16>
__global__ __launch_bounds__((F / 4) * NPB) void agg4h(
    const unsigned short* __restrict__ h, const int2* __restrict__ ninfo,
    const unsigned short* __restrict__ csr,
    const float* __restrict__ dinv, const float* __restrict__ bias,
    float* __restrict__ outf, unsigned short* __restrict__ outh, int n) {
    constexpr int L = F / 4;
    const int local = threadIdx.x / L;
    const int lane = threadIdx.x % L;
    const int node = blockIdx.x * NPB + local;
    if (node >= n) return;

    const ushort4* __restrict__ h4 = (const ushort4*)h;
    const float di = dinv[node];
    const int2 info = ninfo[node];
    const int beg = info.x;
    const int num = info.y;

    float4 acc = u8_to_f4(h4[(size_t)node * L + lane]);  // self term h'[d]

    for (int e = 0; e < num; e += 8) {
        int c[8];
        ushort4 raw[8];
#pragma unroll
        for (int u = 0; u < 8; ++u) {
            int idx = min(e + u, num - 1);
            c[u] = csr[beg + idx];
        }
#pragma unroll
        for (int u = 0; u < 8; ++u) raw[u] = h4[(size_t)c[u] * L + lane];
#pragma unroll
        for (int u = 0; u < 8; ++u) {
            float4 v = u8_to_f4(raw[u]);
            if (e + u < num) acc = add4(v, acc);
        }
    }
    acc.x *= di; acc.y *= di; acc.z *= di; acc.w *= di;
    if (BIAS) {
        const float4 b = ((const float4*)bias)[lane];
        acc.x += b.x; acc.y += b.y; acc.z += b.z; acc.w += b.w;
    }
    if (RELU) {
        acc.x = fmaxf(acc.x, 0.f); acc.y = fmaxf(acc.y, 0.f);
        acc.z = fmaxf(acc.z, 0.f); acc.w = fmaxf(acc.w, 0.f);
    }
    if constexpr (OUTF16) {
        ((ushort4*)outh)[(size_t)node * L + lane] = f4_to_u8(acc);
    } else {
        ((float4*)outf)[(size_t)node * L + lane] = acc;
    }
}

// ---------------------------------------------------------------------------
extern "C" void kernel_launch(void* const* d_in, const int* in_sizes, int n_in,
                              void* d_out, int out_size, void* d_ws, size_t ws_size,
                              hipStream_t stream) {
    const float* x   = (const float*)d_in[0];
    const int*   eix = (const int*)d_in[1];
    const float* W1  = (const float*)d_in[2];
    const float* b1  = (const float*)d_in[3];
    const float* W2  = (const float*)d_in[4];
    const float* b2  = (const float*)d_in[5];
    const float* W3  = (const float*)d_in[6];
    const float* b3  = (const float*)d_in[7];
    float* out = (float*)d_out;

    const int n = NN, E = NE;

    char* p = (char*)d_ws;
    auto alloc = [&](size_t bytes) { void* r = (void*)p; p += align_up(bytes, 256); return r; };
    int2*  ninfo     = (int2*)alloc((size_t)n * 8);
    float* dinv      = (float*)alloc((size_t)n * 4);
    int*   bstart    = (int*)alloc((size_t)(NBKT + 1) * 4);
    int*   base      = (int*)alloc((size_t)P1B * NBKT * 4);
    unsigned* pairs  = (unsigned*)alloc((size_t)E * 4);
    unsigned short* csr = (unsigned short*)alloc((size_t)E * 2);
    unsigned short* w1t = (unsigned short*)alloc((size_t)128 * 256 * 2);
    unsigned short* w2t = (unsigned short*)alloc((size_t)256 * 128 * 2);
    unsigned short* w3t = (unsigned short*)alloc((size_t)128 * 32 * 2);
    unsigned short* xh   = (unsigned short*)alloc((size_t)n * 128 * 2);  // x'  fp16
    unsigned short* agg0 = (unsigned short*)alloc((size_t)n * 128 * 2);  // agg0 fp16
    unsigned short* h2s  = (unsigned short*)alloc((size_t)n * 128 * 2);  // h2' fp16 (scaled)
    unsigned short* x3   = (unsigned short*)alloc((size_t)n * 128 * 2);  // x3  fp16
    unsigned short* h3s  = (unsigned short*)alloc((size_t)n * 32 * 2);   // h3' fp16 (scaled)
    (void)ws_size; (void)in_sizes; (void)n_in; (void)out_size;

    // ---- CSR build: hist(+weight prep) -> colsum+scan -> scatter ->
    //      finalize(+fused x cast)
    bucket_hist<<<P1B, 256, 0, stream>>>(eix, base, W1, W2, W3, w1t, w2t, w3t, E);
    colsum_scan<<<1, 512, 0, stream>>>(base, bstart);
    bucket_scatter<<<P1B, 256, 0, stream>>>(eix, bstart, base, pairs, E);
    bucket_finalize<<<NBKT, 256, 0, stream>>>(pairs, bstart, x, ninfo, dinv, csr, xh, n);

    const int RB = (n + 127) / 128;  // 391 row blocks

    // ---- layer 1 agg: agg0 = A_norm-gather(x') (fp16, 16B loads)
    agg16h<16, false, false><<<(n + 15) / 16, 256, 0, stream>>>(
        xh, ninfo, csr, dinv, nullptr, agg0, n);

    // ---- FUSED gemm1+gemm2: h2' = dinv ⊙ (relu(agg0 @ W1 + b1) @ W2) (fp16)
    gemm12<<<RB, 256, 0, stream>>>(agg0, w1t, w2t, b1, dinv, h2s, n);

    // ---- layer 2 agg: x3 = relu(agg(h2') + b2) (fp16, 16B loads)
    agg16h<16, true, true><<<(n + 15) / 16, 256, 0, stream>>>(
        h2s, ninfo, csr, dinv, b2, x3, n);

    // ---- layer 3: h3' = dinv ⊙ (x3 @ W3) (fp16); out = agg(h3') + b3 (f32)
    gemm_f16<128, 32, 4, 1, false, false, true, true><<<dim3(1, RB), 256, 0, stream>>>(
        x3, w3t, nullptr, dinv, nullptr, h3s, n, 128, 32);
    agg4h<32, 32, true, false, false><<<(n + 31) / 32, 256, 0, stream>>>(
        h3s, ninfo, csr, dinv, b3, out, nullptr, n);
}

// Round 16
// 150.663 us; speedup vs baseline: 1.3364x; 1.0027x over previous
//
#include <hip/hip_runtime.h>
#include <hip/hip_fp16.h>

#define NN 50000
#define NE 800000
#define NBKT 391          // ceil(50000/128) buckets of 128 nodes
#define P1B 256           // blocks in hist/scatter passes

typedef __attribute__((ext_vector_type(8))) _Float16 half8v;  // 8 fp16 in 4 VGPRs
typedef __attribute__((ext_vector_type(4))) float f32x4;

static inline size_t align_up(size_t x, size_t a) { return (x + a - 1) & ~(a - 1); }

union U8 {
    ushort4 u;
    __half2 h[2];
};

__device__ __forceinline__ float4 u8_to_f4(ushort4 uu) {
    U8 c;
    c.u = uu;
    float2 f01 = __half22float2(c.h[0]);
    float2 f23 = __half22float2(c.h[1]);
    return make_float4(f01.x, f01.y, f23.x, f23.y);
}

__device__ __forceinline__ ushort4 f4_to_u8(float4 v) {
    U8 c;
    c.h[0] = __floats2half2_rn(v.x, v.y);
    c.h[1] = __floats2half2_rn(v.z, v.w);
    return c.u;
}

__device__ __forceinline__ float4 add4(float4 v, float4 a) {
    a.x += v.x; a.y += v.y; a.z += v.z; a.w += v.w;
    return a;
}

// async global->LDS, 16B per lane (dest = wave-uniform base + lane*16)
__device__ __forceinline__ void gload_lds16(const unsigned short* g, unsigned short* l) {
    __builtin_amdgcn_global_load_lds(
        (const __attribute__((address_space(1))) unsigned int*)g,
        (__attribute__((address_space(3))) unsigned int*)l,
        16, 0, 0);
}

// int64-vs-int32 edge layout probe (values < 2^31 => odd words zero)
__device__ __forceinline__ int detect64(const int* __restrict__ e) {
    int ok = 1;
    for (int k = 1; k < 64; k += 2) ok &= (e[k] == 0);
    return ok;
}

// ---------------------------------------------------------------------------
// P1: per-block bucket histogram -> plain writes to base[block][bucket];
// spare lanes also do the weight transpose+cast (fused prep_weights)
// ---------------------------------------------------------------------------
__global__ __launch_bounds__(256) void bucket_hist(const int* __restrict__ e,
                                                   int* __restrict__ base,
                                                   const float* __restrict__ W1,
                                                   const float* __restrict__ W2,
                                                   const float* __restrict__ W3,
                                                   unsigned short* __restrict__ w1t,
                                                   unsigned short* __restrict__ w2t,
                                                   unsigned short* __restrict__ w3t,
                                                   int E) {
    __shared__ int hist[NBKT];
    const int is64 = detect64(e);
    for (int t = threadIdx.x; t < NBKT; t += 256) hist[t] = 0;
    __syncthreads();
    const int chunk = (E + P1B - 1) / P1B;
    const int b0 = blockIdx.x * chunk;
    const int b1 = min(E, b0 + chunk);
    for (int i = b0 + threadIdx.x; i < b1; i += 256) {
        int d = is64 ? e[2 * (E + i)] : e[E + i];
        atomicAdd(&hist[d >> 7], 1);
    }
    // fused weight prep (grid-stride over 69632 elems)
    for (int i = blockIdx.x * 256 + threadIdx.x; i < 69632; i += P1B * 256) {
        const float* W;
        unsigned short* th;
        int K, M, j;
        if (i < 32768)      { W = W1; th = w1t; K = 128; M = 256; j = i; }
        else if (i < 65536) { W = W2; th = w2t; K = 256; M = 128; j = i - 32768; }
        else                { W = W3; th = w3t; K = 128; M = 32;  j = i - 65536; }
        int k = j / M, m = j % M;
        th[(size_t)m * K + k] = __half_as_ushort(__float2half_rn(W[j]));
    }
    __syncthreads();
    for (int t = threadIdx.x; t < NBKT; t += 256)
        base[blockIdx.x * NBKT + t] = hist[t];
}

// ---------------------------------------------------------------------------
// P2: column prefix over base[P1B][NBKT] (per-block exclusive offsets) +
// bucket exclusive scan -> bstart[0..NBKT]. One block, 512 threads.
// ---------------------------------------------------------------------------
__global__ __launch_bounds__(512) void colsum_scan(int* __restrict__ base,
                                                   int* __restrict__ bstart) {
    __shared__ int s[512];
    const int t = threadIdx.x;
    int total = 0;
    if (t < NBKT) {
        for (int b0 = 0; b0 < P1B; b0 += 8) {
            int v[8];
#pragma unroll
            for (int u = 0; u < 8; ++u) v[u] = base[(size_t)(b0 + u) * NBKT + t];
#pragma unroll
            for (int u = 0; u < 8; ++u) {
                int nv = v[u];
                base[(size_t)(b0 + u) * NBKT + t] = total;
                total += nv;
            }
        }
    }
    s[t] = (t < NBKT) ? total : 0;
    __syncthreads();
    for (int off = 1; off < 512; off <<= 1) {
        int tv = (t >= off) ? s[t - off] : 0;
        __syncthreads();
        s[t] += tv;
        __syncthreads();
    }
    if (t < NBKT) bstart[t] = s[t] - total;
    if (t == 0) bstart[NBKT] = s[511];  // total = E
}

// ---------------------------------------------------------------------------
// P3: scatter packed edges (src u16 | dst_local u7) into bucket-binned order
// ---------------------------------------------------------------------------
__global__ __launch_bounds__(256) void bucket_scatter(const int* __restrict__ e,
                                                      const int* __restrict__ bstart,
                                                      const int* __restrict__ base,
                                                      unsigned* __restrict__ pairs, int E) {
    __shared__ int cur[NBKT];
    const int is64 = detect64(e);
    for (int t = threadIdx.x; t < NBKT; t += 256)
        cur[t] = bstart[t] + base[blockIdx.x * NBKT + t];
    __syncthreads();
    const int chunk = (E + P1B - 1) / P1B;
    const int b0 = blockIdx.x * chunk;
    const int b1 = min(E, b0 + chunk);
    for (int i = b0 + threadIdx.x; i < b1; i += 256) {
        int s = is64 ? e[2 * i] : e[i];
        int d = is64 ? e[2 * (E + i)] : e[E + i];
        int pos = atomicAdd(&cur[d >> 7], 1);
        pairs[pos] = (unsigned)s | ((unsigned)(d & 127) << 16);
    }
}

// ---------------------------------------------------------------------------
// P4: one block per bucket. (1) local deg count + scan -> ninfo{beg,deg}/dinv;
// (2) LDS-cursor scatter src -> contiguous u16 CSR range; (3) fused cast of
// this bucket's x rows to pre-scaled fp16 (x' = dinv ⊙ x).
// ---------------------------------------------------------------------------
__global__ __launch_bounds__(256) void bucket_finalize(const unsigned* __restrict__ pairs,
                                                       const int* __restrict__ bstart,
                                                       const float* __restrict__ x,
                                                       int2* __restrict__ ninfo,
                                                       float* __restrict__ dinv,
                                                       unsigned short* __restrict__ csr,
                                                       unsigned short* __restrict__ xh, int n) {
    __shared__ int ldeg[128];
    __shared__ int lscan[128];
    __shared__ int cur[128];
    __shared__ float sdinv[128];
    const int bkt = blockIdx.x;
    const int s0 = bstart[bkt], s1 = bstart[bkt + 1];
    if (threadIdx.x < 128) ldeg[threadIdx.x] = 0;
    __syncthreads();
    for (int i = s0 + threadIdx.x; i < s1; i += 256)
        atomicAdd(&ldeg[pairs[i] >> 16], 1);
    __syncthreads();
    if (threadIdx.x < 128) lscan[threadIdx.x] = ldeg[threadIdx.x];
    __syncthreads();
    for (int off = 1; off < 128; off <<= 1) {
        int v = 0;
        if (threadIdx.x < 128 && threadIdx.x >= off) v = lscan[threadIdx.x - off];
        __syncthreads();
        if (threadIdx.x < 128) lscan[threadIdx.x] += v;
        __syncthreads();
    }
    if (threadIdx.x < 128) {
        int node = (bkt << 7) + threadIdx.x;
        int exc = s0 + lscan[threadIdx.x] - ldeg[threadIdx.x];
        cur[threadIdx.x] = exc;
        float di = rsqrtf((float)(ldeg[threadIdx.x] + 1));  // +1 self-loop
        sdinv[threadIdx.x] = di;
        if (node < n) {
            ninfo[node] = make_int2(exc, ldeg[threadIdx.x]);
            dinv[node] = di;
        }
    }
    __syncthreads();
    // csr scatter (u16 src)
    for (int i = s0 + threadIdx.x; i < s1; i += 256) {
        unsigned pr = pairs[i];
        int pos = atomicAdd(&cur[pr >> 16], 1);
        csr[pos] = (unsigned short)(pr & 0xFFFFu);
    }
    // fused cast: x rows of this bucket -> pre-scaled fp16 (linear, coalesced)
    for (int idx = threadIdx.x; idx < 128 * 32; idx += 256) {
        int ln = idx >> 5;         // local node
        int c4 = idx & 31;         // float4 chunk within row (128 feats)
        int node = (bkt << 7) + ln;
        if (node < n) {
            float4 v = ((const float4*)x)[(size_t)node * 32 + c4];
            float s = sdinv[ln];
            v.x *= s; v.y *= s; v.z *= s; v.w *= s;
            ((ushort4*)xh)[(size_t)node * 32 + c4] = f4_to_u8(v);
        }
    }
}

// ---------------------------------------------------------------------------
// FUSED layer-1+2 GEMM: per 128-row tile,
//   h1 = relu(agg0 @ W1 + b1)   [128 x 256]  (kept in LDS, never hits HBM)
//   h2' = dinv ⊙ (h1 @ W2)      [128 x 128]  (fp16 out)
// ---------------------------------------------------------------------------
__global__ __launch_bounds__(256) void gemm12(
    const unsigned short* __restrict__ A,     // agg0 [N][128] fp16
    const unsigned short* __restrict__ W1t,   // [256][128] fp16
    const unsigned short* __restrict__ W2t,   // [128][256] fp16
    const float* __restrict__ b1,
    const float* __restrict__ dinv,
    unsigned short* __restrict__ H2,          // [N][128] fp16 (scaled)
    int N) {
    __shared__ unsigned short sA[128][128];   // 32KB, swizzled chunks
    __shared__ unsigned short sW[128][128];   // 32KB, swizzled, reused 4x
    __shared__ unsigned short sH[128][136];   // 34.8KB, padded (16B-aligned rows)

    const int tid = threadIdx.x;
    const int lane = tid & 63;
    const int w = tid >> 6;
    const int wr = w >> 1, wc = w & 1;        // 2x2 waves over 128x128
    const int row0 = blockIdx.x * 128;
    const int rsel = lane & 15;
    const int cq = lane >> 4;                 // 0..3

    // stage A tile (rows x K=128): 2048 16B-chunks, slot s holds chunk (s&8)|((s^r)&7)
#pragma unroll
    for (int b = 0; b < 2048; b += 256) {
        int idx = b + tid;
        int r = idx >> 4, s = idx & 15;
        int gr = row0 + r;
        int sp = (s & 8) | ((s ^ r) & 7);
        if (gr < N) gload_lds16(&A[(size_t)gr * 128 + sp * 8], &sA[0][0] + idx * 8);
        // rows >= N: stale LDS; those output rows are never stored
    }

    f32x4 acc2[4][4];
#pragma unroll
    for (int m = 0; m < 4; ++m)
#pragma unroll
        for (int nn = 0; nn < 4; ++nn) {
            f32x4 z = {0.f, 0.f, 0.f, 0.f};
            acc2[m][nn] = z;
        }

    for (int half = 0; half < 2; ++half) {
        __syncthreads();  // drains A-stage (half 0) / prior acc2 reads of sW (half 1)
        // stage W1 half: h1-cols half*128..+127, K=128
#pragma unroll
        for (int b = 0; b < 2048; b += 256) {
            int idx = b + tid;
            int r = idx >> 4, s = idx & 15;
            int sp = (s & 8) | ((s ^ r) & 7);
            gload_lds16(&W1t[(size_t)(half * 128 + r) * 128 + sp * 8], &sW[0][0] + idx * 8);
        }
        __syncthreads();

        // acc1 = sA @ sW^T   (output 128x128, K=128)
        f32x4 acc1[4][4];
#pragma unroll
        for (int m = 0; m < 4; ++m)
#pragma unroll
            for (int nn = 0; nn < 4; ++nn) {
                f32x4 z = {0.f, 0.f, 0.f, 0.f};
                acc1[m][nn] = z;
            }
#pragma unroll
        for (int ks = 0; ks < 4; ++ks) {
            half8v af[4], wf[4];
            int c = ks * 4 + cq;
#pragma unroll
            for (int m = 0; m < 4; ++m) {
                int rr = wr * 64 + m * 16 + rsel;
                int cp = (c & 8) | ((c ^ rr) & 7);
                af[m] = *(const half8v*)&sA[rr][cp * 8];
            }
#pragma unroll
            for (int nn = 0; nn < 4; ++nn) {
                int rr = wc * 64 + nn * 16 + rsel;
                int cp = (c & 8) | ((c ^ rr) & 7);
                wf[nn] = *(const half8v*)&sW[rr][cp * 8];
            }
#pragma unroll
            for (int m = 0; m < 4; ++m)
#pragma unroll
                for (int nn = 0; nn < 4; ++nn)
                    acc1[m][nn] = __builtin_amdgcn_mfma_f32_16x16x32_f16(af[m], wf[nn], acc1[m][nn], 0, 0, 0);
        }

        // bias+relu -> fp16 -> sH (row-major h1 half)
        float b1v[4];
#pragma unroll
        for (int nn = 0; nn < 4; ++nn)
            b1v[nn] = b1[half * 128 + wc * 64 + nn * 16 + rsel];
#pragma unroll
        for (int m = 0; m < 4; ++m)
#pragma unroll
            for (int nn = 0; nn < 4; ++nn)
#pragma unroll
                for (int r = 0; r < 4; ++r) {
                    int rl = wr * 64 + m * 16 + cq * 4 + r;
                    int cl = wc * 64 + nn * 16 + rsel;
                    float v = fmaxf(acc1[m][nn][r] + b1v[nn], 0.f);
                    sH[rl][cl] = __half_as_ushort(__float2half_rn(v));
                }
        __syncthreads();  // sH complete; safe to overwrite sW

        // stage W2 K-slice: rows (h2 cols) 0..127, K in [half*128, half*128+128)
#pragma unroll
        for (int b = 0; b < 2048; b += 256) {
            int idx = b + tid;
            int r = idx >> 4, s = idx & 15;
            int sp = (s & 8) | ((s ^ r) & 7);
            gload_lds16(&W2t[(size_t)r * 256 + half * 128 + sp * 8], &sW[0][0] + idx * 8);
        }
        __syncthreads();

        // acc2 += sH @ sW^T  (K=128 local)
#pragma unroll
        for (int ks = 0; ks < 4; ++ks) {
            half8v ah[4], wf[4];
            int koff = ks * 32 + cq * 8;
            int c = ks * 4 + cq;
#pragma unroll
            for (int m = 0; m < 4; ++m) {
                int rr = wr * 64 + m * 16 + rsel;
                ah[m] = *(const half8v*)&sH[rr][koff];
            }
#pragma unroll
            for (int nn = 0; nn < 4; ++nn) {
                int rr = wc * 64 + nn * 16 + rsel;
                int cp = (c & 8) | ((c ^ rr) & 7);
                wf[nn] = *(const half8v*)&sW[rr][cp * 8];
            }
#pragma unroll
            for (int m = 0; m < 4; ++m)
#pragma unroll
                for (int nn = 0; nn < 4; ++nn)
                    acc2[m][nn] = __builtin_amdgcn_mfma_f32_16x16x32_f16(ah[m], wf[nn], acc2[m][nn], 0, 0, 0);
        }
    }

    // epilogue: h2' = dinv ⊙ acc2, fp16 out
#pragma unroll
    for (int m = 0; m < 4; ++m)
#pragma unroll
        for (int r = 0; r < 4; ++r) {
            int row = row0 + wr * 64 + m * 16 + cq * 4 + r;
            if (row >= N) continue;
            float rs = dinv[row];
#pragma unroll
            for (int nn = 0; nn < 4; ++nn) {
                int col = wc * 64 + nn * 16 + rsel;
                H2[(size_t)row * 128 + col] =
                    __half_as_ushort(__float2half_rn(acc2[m][nn][r] * rs));
            }
        }
}

// ---------------------------------------------------------------------------
// fp16 MFMA GEMM (single): C[N,M] = A[N,K](fp16) @ W[K,M](fp16, transposed),
// KS=64, gload_lds + chunk-XOR swizzle. OUTF16 / SCALE as before.
// ---------------------------------------------------------------------------
template <int BM, int BN, int WM, int WN, bool BIAS, bool RELU, bool OUTF16, bool SCALE>
__global__ __launch_bounds__(256) void gemm_f16(
    const unsigned short* __restrict__ A,
    const unsigned short* __restrict__ Wt,
    const float* __restrict__ bias, const float* __restrict__ dscale,
    float* __restrict__ Cf, unsigned short* __restrict__ Ch,
    int N, int K, int M) {
    constexpr int KS = 64;
    constexpr int WTM = BM / WM;
    constexpr int WTN = BN / WN;
    constexpr int FM = WTM / 16;
    constexpr int FN = WTN / 16;
    constexpr int ACH = BM * 8;
    constexpr int WCH = BN * 8;
    __shared__ unsigned short sA[BM][KS], sW[BN][KS];

    const int tid = threadIdx.x;
    const int lane = tid & 63;
    const int w = tid >> 6;
    const int wr = w / WN, wc = w % WN;
    const int row0 = blockIdx.y * BM;
    const int col0 = blockIdx.x * BN;

    f32x4 acc[FM][FN];
#pragma unroll
    for (int m = 0; m < FM; ++m)
#pragma unroll
        for (int nn = 0; nn < FN; ++nn) {
            f32x4 z = {0.f, 0.f, 0.f, 0.f};
            acc[m][nn] = z;
        }

    for (int k0 = 0; k0 < K; k0 += KS) {
#pragma unroll
        for (int b = 0; b < ACH; b += 256) {
            int idx = b + tid;
            int r = idx >> 3, s = idx & 7;
            int gr = row0 + r;
            int sp = s ^ (r & 7);
            if (gr < N)
                gload_lds16(&A[(size_t)gr * K + k0 + sp * 8], &sA[0][0] + idx * 8);
        }
#pragma unroll
        for (int b = 0; b < WCH; b += 256) {
            int idx = b + tid;
            int r = idx >> 3, s = idx & 7;
            int gc = col0 + r;
            int sp = s ^ (r & 7);
            gload_lds16(&Wt[(size_t)gc * K + k0 + sp * 8], &sW[0][0] + idx * 8);
        }
        __syncthreads();

        half8v af[FM][2], wf[FN][2];
        const int rsel = lane & 15;
        const int cb = lane >> 4;
#pragma unroll
        for (int m = 0; m < FM; ++m) {
            int rr = wr * WTM + m * 16 + rsel;
            af[m][0] = *(const half8v*)&sA[rr][((cb) ^ (rr & 7)) * 8];
            af[m][1] = *(const half8v*)&sA[rr][((cb + 4) ^ (rr & 7)) * 8];
        }
#pragma unroll
        for (int nn = 0; nn < FN; ++nn) {
            int rr = wc * WTN + nn * 16 + rsel;
            wf[nn][0] = *(const half8v*)&sW[rr][((cb) ^ (rr & 7)) * 8];
            wf[nn][1] = *(const half8v*)&sW[rr][((cb + 4) ^ (rr & 7)) * 8];
        }
#pragma unroll
        for (int m = 0; m < FM; ++m)
#pragma unroll
            for (int nn = 0; nn < FN; ++nn) {
                acc[m][nn] = __builtin_amdgcn_mfma_f32_16x16x32_f16(af[m][0], wf[nn][0], acc[m][nn], 0, 0, 0);
                acc[m][nn] = __builtin_amdgcn_mfma_f32_16x16x32_f16(af[m][1], wf[nn][1], acc[m][nn], 0, 0, 0);
            }
        __syncthreads();
    }

#pragma unroll
    for (int m = 0; m < FM; ++m) {
#pragma unroll
        for (int r = 0; r < 4; ++r) {
            int row = row0 + wr * WTM + m * 16 + (lane >> 4) * 4 + r;
            if (row >= N) continue;
            float rs = SCALE ? dscale[row] : 1.f;
#pragma unroll
            for (int nn = 0; nn < FN; ++nn) {
                int col = col0 + wc * WTN + nn * 16 + (lane & 15);
                float v = acc[m][nn][r];
                if (BIAS) v += bias[col];
                if (RELU) v = fmaxf(v, 0.f);
                if (SCALE) v *= rs;
                if constexpr (OUTF16) {
                    Ch[(size_t)row * M + col] = __half_as_ushort(__float2half_rn(v));
                } else {
                    Cf[(size_t)row * M + col] = v;
                }
            }
        }
    }
}

// ---------------------------------------------------------------------------
// F=128 CSR aggregation, 16 lanes/node x 16B (uint4) loads, 8-deep batch:
// out[d] = dinv[d] * (h'[d] + Σ h'[s]) (+bias, relu), fp16 out.
// ---------------------------------------------------------------------------
template <int NPB, bool BIAS, bool RELU>
__global__ __launch_bounds__(16 * NPB) void agg16h(
    const unsigned short* __restrict__ h, const int2* __restrict__ ninfo,
    const unsigned short* __restrict__ csr,
    const float* __restrict__ dinv, const float* __restrict__ bias,
    unsigned short* __restrict__ outh, int n) {
    const int local = threadIdx.x >> 4;
    const int lane = threadIdx.x & 15;
    const int node = blockIdx.x * NPB + local;
    if (node >= n) return;

    const uint4* __restrict__ h16 = (const uint4*)h;  // 16B chunks; 16 per row
    const float di = dinv[node];
    const int2 info = ninfo[node];
    const int beg = info.x;
    const int num = info.y;

    uint4 self = h16[(size_t)node * 16 + lane];
    float4 accA = u8_to_f4(*(const ushort4*)&self.x);
    float4 accB = u8_to_f4(*(const ushort4*)&self.z);

    for (int e = 0; e < num; e += 8) {
        int c[8];
        uint4 raw[8];
#pragma unroll
        for (int u = 0; u < 8; ++u) {
            int idx = min(e + u, num - 1);           // clamp: dup loads are L1-hot
            c[u] = csr[beg + idx];
        }
#pragma unroll
        for (int u = 0; u < 8; ++u) raw[u] = h16[(size_t)c[u] * 16 + lane];
#pragma unroll
        for (int u = 0; u < 8; ++u) {
            if (e + u < num) {                       // predicated; order unchanged
                accA = add4(u8_to_f4(*(const ushort4*)&raw[u].x), accA);
                accB = add4(u8_to_f4(*(const ushort4*)&raw[u].z), accB);
            }
        }
    }
    accA.x *= di; accA.y *= di; accA.z *= di; accA.w *= di;
    accB.x *= di; accB.y *= di; accB.z *= di; accB.w *= di;
    if (BIAS) {
        const float4* b4 = (const float4*)bias;
        float4 bA = b4[lane * 2], bB = b4[lane * 2 + 1];
        accA.x += bA.x; accA.y += bA.y; accA.z += bA.z; accA.w += bA.w;
        accB.x += bB.x; accB.y += bB.y; accB.z += bB.z; accB.w += bB.w;
    }
    if (RELU) {
        accA.x = fmaxf(accA.x, 0.f); accA.y = fmaxf(accA.y, 0.f);
        accA.z = fmaxf(accA.z, 0.f); accA.w = fmaxf(accA.w, 0.f);
        accB.x = fmaxf(accB.x, 0.f); accB.y = fmaxf(accB.y, 0.f);
        accB.z = fmaxf(accB.z, 0.f); accB.w = fmaxf(accB.w, 0.f);
    }
    uint4 o;
    *(ushort4*)&o.x = f4_to_u8(accA);
    *(ushort4*)&o.z = f4_to_u8(accB);
    ((uint4*)outh)[(size_t)node * 16 + lane] = o;
}

// ---------------------------------------------------------------------------
// Final F=32 CSR aggregation, 4 lanes/node x 16B (uint4) loads, 8-deep batch:
// out[d] = dinv[d]*(h'[d] + Σ h'[s]) + bias, f32 out (one 64B row = 4x16B).
// Per-feature f32 add order identical to prior version (bit-identical).
// ---------------------------------------------------------------------------
template <int NPB>
__global__ __launch_bounds__(4 * NPB) void agg32f(
    const unsigned short* __restrict__ h, const int2* __restrict__ ninfo,
    const unsigned short* __restrict__ csr,
    const float* __restrict__ dinv, const float* __restrict__ bias,
    float* __restrict__ outf, int n) {
    const int local = threadIdx.x >> 2;
    const int lane = threadIdx.x & 3;
    const int node = blockIdx.x * NPB + local;
    if (node >= n) return;

    const uint4* __restrict__ h16 = (const uint4*)h;  // 16B chunks; 4 per row
    const float di = dinv[node];
    const int2 info = ninfo[node];
    const int beg = info.x;
    const int num = info.y;

    uint4 self = h16[(size_t)node * 4 + lane];
    float4 accA = u8_to_f4(*(const ushort4*)&self.x);
    float4 accB = u8_to_f4(*(const ushort4*)&self.z);

    for (int e = 0; e < num; e += 8) {
        int c[8];
        uint4 raw[8];
#pragma unroll
        for (int u = 0; u < 8; ++u) {
            int idx = min(e + u, num - 1);           // clamp: dup loads are L1-hot
            c[u] = csr[beg + idx];
        }
#pragma unroll
        for (int u = 0; u < 8; ++u) raw[u] = h16[(size_t)c[u] * 4 + lane];
#pragma unroll
        for (int u = 0; u < 8; ++u) {
            if (e + u < num) {                       // predicated; order unchanged
                accA = add4(u8_to_f4(*(const ushort4*)&raw[u].x), accA);
                accB = add4(u8_to_f4(*(const ushort4*)&raw[u].z), accB);
            }
        }
    }
    accA.x *= di; accA.y *= di; accA.z *= di; accA.w *= di;
    accB.x *= di; accB.y *= di; accB.z *= di; accB.w *= di;
    {
        const float4* b4 = (const float4*)bias;
        float4 bA = b4[lane * 2], bB = b4[lane * 2 + 1];
        accA.x += bA.x; accA.y += bA.y; accA.z += bA.z; accA.w += bA.w;
        accB.x += bB.x; accB.y += bB.y; accB.z += bB.z; accB.w += bB.w;
    }
    float4* o4 = (float4*)outf;
    o4[(size_t)node * 8 + lane * 2]     = accA;
    o4[(size_t)node * 8 + lane * 2 + 1] = accB;
}

// ---------------------------------------------------------------------------
extern "C" void kernel_launch(void* const* d_in, const int* in_sizes, int n_in,
                              void* d_out, int out_size, void* d_ws, size_t ws_size,
                              hipStream_t stream) {
    const float* x   = (const float*)d_in[0];
    const int*   eix = (const int*)d_in[1];
    const float* W1  = (const float*)d_in[2];
    const float* b1  = (const float*)d_in[3];
    const float* W2  = (const float*)d_in[4];
    const float* b2  = (const float*)d_in[5];
    const float* W3  = (const float*)d_in[6];
    const float* b3  = (const float*)d_in[7];
    float* out = (float*)d_out;

    const int n = NN, E = NE;

    char* p = (char*)d_ws;
    auto alloc = [&](size_t bytes) { void* r = (void*)p; p += align_up(bytes, 256); return r; };
    int2*  ninfo     = (int2*)alloc((size_t)n * 8);
    float* dinv      = (float*)alloc((size_t)n * 4);
    int*   bstart    = (int*)alloc((size_t)(NBKT + 1) * 4);
    int*   base      = (int*)alloc((size_t)P1B * NBKT * 4);
    unsigned* pairs  = (unsigned*)alloc((size_t)E * 4);
    unsigned short* csr = (unsigned short*)alloc((size_t)E * 2);
    unsigned short* w1t = (unsigned short*)alloc((size_t)128 * 256 * 2);
    unsigned short* w2t = (unsigned short*)alloc((size_t)256 * 128 * 2);
    unsigned short* w3t = (unsigned short*)alloc((size_t)128 * 32 * 2);
    unsigned short* xh   = (unsigned short*)alloc((size_t)n * 128 * 2);  // x'  fp16
    unsigned short* agg0 = (unsigned short*)alloc((size_t)n * 128 * 2);  // agg0 fp16
    unsigned short* h2s  = (unsigned short*)alloc((size_t)n * 128 * 2);  // h2' fp16 (scaled)
    unsigned short* x3   = (unsigned short*)alloc((size_t)n * 128 * 2);  // x3  fp16
    unsigned short* h3s  = (unsigned short*)alloc((size_t)n * 32 * 2);   // h3' fp16 (scaled)
    (void)ws_size; (void)in_sizes; (void)n_in; (void)out_size;

    // ---- CSR build: hist(+weight prep) -> colsum+scan -> scatter ->
    //      finalize(+fused x cast)
    bucket_hist<<<P1B, 256, 0, stream>>>(eix, base, W1, W2, W3, w1t, w2t, w3t, E);
    colsum_scan<<<1, 512, 0, stream>>>(base, bstart);
    bucket_scatter<<<P1B, 256, 0, stream>>>(eix, bstart, base, pairs, E);
    bucket_finalize<<<NBKT, 256, 0, stream>>>(pairs, bstart, x, ninfo, dinv, csr, xh, n);

    const int RB = (n + 127) / 128;  // 391 row blocks

    // ---- layer 1 agg: agg0 = A_norm-gather(x') (fp16, 16B loads)
    agg16h<16, false, false><<<(n + 15) / 16, 256, 0, stream>>>(
        xh, ninfo, csr, dinv, nullptr, agg0, n);

    // ---- FUSED gemm1+gemm2: h2' = dinv ⊙ (relu(agg0 @ W1 + b1) @ W2) (fp16)
    gemm12<<<RB, 256, 0, stream>>>(agg0, w1t, w2t, b1, dinv, h2s, n);

    // ---- layer 2 agg: x3 = relu(agg(h2') + b2) (fp16, 16B loads)
    agg16h<16, true, true><<<(n + 15) / 16, 256, 0, stream>>>(
        h2s, ninfo, csr, dinv, b2, x3, n);

    // ---- layer 3: h3' = dinv ⊙ (x3 @ W3) (fp16); out = agg(h3') + b3 (f32)
    gemm_f16<128, 32, 4, 1, false, false, true, true><<<dim3(1, RB), 256, 0, stream>>>(
        x3, w3t, nullptr, dinv, nullptr, h3s, n, 128, 32);
    agg32f<64><<<(n + 63) / 64, 256, 0, stream>>>(
        h3s, ninfo, csr, dinv, b3, out, n);
}